// Round 2
// baseline (4099.029 us; speedup 1.0000x reference)
//
#include <hip/hip_runtime.h>
#include <stdint.h>

// Problem constants (fixed by reference)
#define NSRC 50000
#define NTGT 50000
#define NE   320000
#define DIN  256
#define HID  256
#define DOUT 16

// ---------------------------------------------------------------------------
// Threefry-2x32 (exact JAX implementation: 20 rounds, 5 key injections)
// ---------------------------------------------------------------------------
__host__ __device__ constexpr uint64_t tf2x32(uint32_t k0, uint32_t k1,
                                              uint32_t x0, uint32_t x1) {
  uint32_t ks2 = k0 ^ k1 ^ 0x1BD11BDAu;
  x0 += k0; x1 += k1;
#define TF_ROT(x, r) (((x) << (r)) | ((x) >> (32 - (r))))
#define TF_RND(r) { x0 += x1; x1 = TF_ROT(x1, r) ^ x0; }
  TF_RND(13) TF_RND(15) TF_RND(26) TF_RND(6)
  x0 += k1;  x1 += ks2 + 1u;
  TF_RND(17) TF_RND(29) TF_RND(16) TF_RND(24)
  x0 += ks2; x1 += k0 + 2u;
  TF_RND(13) TF_RND(15) TF_RND(26) TF_RND(6)
  x0 += k0;  x1 += k1 + 3u;
  TF_RND(17) TF_RND(29) TF_RND(16) TF_RND(24)
  x0 += k1;  x1 += ks2 + 4u;
  TF_RND(13) TF_RND(15) TF_RND(26) TF_RND(6)
  x0 += ks2; x1 += k0 + 5u;
#undef TF_RND
#undef TF_ROT
  return (uint64_t(x0) << 32) | uint64_t(x1);
}

// fold_in(key(42), i) == threefry((0,42), (0,i)) -> new key (k0=out0, k1=out1)
constexpr uint64_t FOLD[4] = {
  tf2x32(0u, 42u, 0u, 0u),
  tf2x32(0u, 42u, 0u, 1u),
  tf2x32(0u, 42u, 0u, 2u),
  tf2x32(0u, 42u, 0u, 3u),
};

// ---------------------------------------------------------------------------
// Dropout: JAX partitionable random_bits (default since jax 0.5):
//   bits[j] = out0 ^ out1 of threefry(key, (0, j))
//   u = bitcast((bits>>9)|0x3f800000) - 1.0 ;  keep iff u < 0.9 ; x *= 1/0.9
// ---------------------------------------------------------------------------
__global__ __launch_bounds__(256) void dropout_kernel(float* __restrict__ x,
                                                      uint32_t k0, uint32_t k1,
                                                      int n4) {
  int i = blockIdx.x * 256 + threadIdx.x;
  if (i >= n4) return;
  float4 v = ((float4*)x)[i];
  float* pv = &v.x;
  uint32_t j = uint32_t(i) * 4u;
#pragma unroll
  for (int t = 0; t < 4; ++t) {
    uint64_t r = tf2x32(k0, k1, 0u, j + uint32_t(t));
    uint32_t bits = uint32_t(r >> 32) ^ uint32_t(r);
    float u = __uint_as_float((bits >> 9) | 0x3f800000u) - 1.0f;
    pv[t] = (u < 0.9f) ? pv[t] * (1.0f / 0.9f) : 0.0f;
  }
  ((float4*)x)[i] = v;
}

// ---------------------------------------------------------------------------
// Segment-sum scatter: 4 edges per 256-thread block, 64 lanes x float4 each
// ---------------------------------------------------------------------------
__global__ __launch_bounds__(256) void scatter_kernel(const float* __restrict__ xin,
                                                      const int* __restrict__ ei,
                                                      float* __restrict__ msum,
                                                      float* __restrict__ cnt,
                                                      int nEdges) {
  int e = blockIdx.x * 4 + (threadIdx.x >> 6);
  int lane = threadIdx.x & 63;
  if (e >= nEdges) return;
  int src = ei[e];
  int dst = ei[nEdges + e];
  const float4 v = *(const float4*)(xin + (size_t)src * DIN + lane * 4);
  float* mp = msum + (size_t)dst * DIN + lane * 4;
  atomicAdd(mp + 0, v.x);
  atomicAdd(mp + 1, v.y);
  atomicAdd(mp + 2, v.z);
  atomicAdd(mp + 3, v.w);
  if (lane == 0) atomicAdd(cnt + dst, 1.0f);
}

__global__ __launch_bounds__(256) void finalize_mean(float* __restrict__ m,
                                                     const float* __restrict__ cnt,
                                                     int nRows) {
  int row = blockIdx.x * 4 + (threadIdx.x >> 6);
  int lane = threadIdx.x & 63;
  if (row >= nRows) return;
  float c = fmaxf(cnt[row], 1.0f);
  float4* p = (float4*)(m + (size_t)row * DIN) + lane;
  float4 v = *p;
  v.x /= c; v.y /= c; v.z /= c; v.w /= c;
  *p = v;
}

// ---------------------------------------------------------------------------
// Fused dual GEMM: C = leaky( A1@W1 + A2@W2 + bias ), fp32, 64x64 tile, BK=32
// ---------------------------------------------------------------------------
#define BM 64
#define BN 64
#define BK 32

__global__ __launch_bounds__(256) void gemm_dual(const float* __restrict__ A1,
                                                 const float* __restrict__ A2,
                                                 const float* __restrict__ W1,
                                                 const float* __restrict__ W2,
                                                 const float* __restrict__ bias,
                                                 float* __restrict__ C, int M) {
  __shared__ float sA[BK][BM + 4];  // k-major (transposed), pad keeps 16B align
  __shared__ float sB[BK][BN];
  int tid = threadIdx.x;
  int mbase = blockIdx.x * BM;
  int nbase = blockIdx.y * BN;
  int tm = tid >> 4;   // 0..15 -> rows tm*4..+3
  int tn = tid & 15;   // 0..15 -> cols tn*4..+3
  float acc[4][4] = {};

  int la_c = tid & 31;   // A col within BK
  int la_r = tid >> 5;   // A row 0..7, step 8
  int lb_r = tid >> 4;   // B row 0..15, step 16
  int lb_c = (tid & 15) * 4;

  for (int phase = 0; phase < 2; ++phase) {
    const float* A = phase ? A2 : A1;
    const float* W = phase ? W2 : W1;
    for (int kt = 0; kt < DIN; kt += BK) {
#pragma unroll
      for (int rr = 0; rr < BM; rr += 8) {
        int row = mbase + rr + la_r;
        row = row < M ? row : M - 1;  // clamp; garbage rows masked at store
        sA[la_c][rr + la_r] = A[(size_t)row * DIN + kt + la_c];
      }
#pragma unroll
      for (int rr = 0; rr < BK; rr += 16) {
        const float4 w = *(const float4*)(W + (size_t)(kt + rr + lb_r) * HID + nbase + lb_c);
        *(float4*)&sB[rr + lb_r][lb_c] = w;
      }
      __syncthreads();
#pragma unroll
      for (int kk = 0; kk < BK; ++kk) {
        float4 a = *(float4*)&sA[kk][tm * 4];
        float4 b = *(float4*)&sB[kk][tn * 4];
        float av[4] = {a.x, a.y, a.z, a.w};
        float bv[4] = {b.x, b.y, b.z, b.w};
#pragma unroll
        for (int i = 0; i < 4; ++i)
#pragma unroll
          for (int j = 0; j < 4; ++j) acc[i][j] += av[i] * bv[j];
      }
      __syncthreads();
    }
  }

  float4 bb = *(const float4*)(bias + nbase + tn * 4);
  float bv[4] = {bb.x, bb.y, bb.z, bb.w};
#pragma unroll
  for (int i = 0; i < 4; ++i) {
    int row = mbase + tm * 4 + i;
    if (row < M) {
      float4 o;
      float* ov = &o.x;
#pragma unroll
      for (int j = 0; j < 4; ++j) {
        float v = acc[i][j] + bv[j];
        ov[j] = v >= 0.0f ? v : 0.01f * v;  // leaky_relu
      }
      *(float4*)(C + (size_t)row * HID + nbase + tn * 4) = o;
    }
  }
}

// ---------------------------------------------------------------------------
// Final projection: [M,256] @ [256,16] + bout
// ---------------------------------------------------------------------------
__global__ __launch_bounds__(256) void out_gemm(const float* __restrict__ X,
                                                const float* __restrict__ Wout,
                                                const float* __restrict__ bout,
                                                float* __restrict__ C, int M) {
  __shared__ float sW[DIN * DOUT];  // 4096 floats
  int tid = threadIdx.x;
#pragma unroll
  for (int i = 0; i < (DIN * DOUT) / 256; ++i) sW[i * 256 + tid] = Wout[i * 256 + tid];
  __syncthreads();
  int r = tid >> 4;
  int c = tid & 15;
  int row = blockIdx.x * 16 + r;
  if (row >= M) return;
  float acc = bout[c];
  const float* xp = X + (size_t)row * DIN;
#pragma unroll 4
  for (int k = 0; k < DIN; k += 4) {
    float4 xv = *(const float4*)(xp + k);
    acc += xv.x * sW[(k + 0) * DOUT + c];
    acc += xv.y * sW[(k + 1) * DOUT + c];
    acc += xv.z * sW[(k + 2) * DOUT + c];
    acc += xv.w * sW[(k + 3) * DOUT + c];
  }
  C[(size_t)row * DOUT + c] = acc;
}

// ---------------------------------------------------------------------------
// Workspace layout (floats), total 3F + NTGT + NSRC = 38.5M fl = 154 MB:
//   B0 [F]: m_t(L0), then reused as x_s(1) (output of L0 new_s gemm)
//   B1 [F]: m_s (both layers)
//   B2 [F]: x_t(1) (L0 new_t output), then reused as x_s(2) (L1 new_s output)
//   cnt_t [NTGT], cnt_s [NSRC]
// Reuse is safe: single stream => kernels execute in launch order, and every
// overwrite happens in a kernel launched AFTER the last reader.
// NOTE: layer-1 target-side (new_t, x_t(2)) is dead code — the reference
// returns x_s @ Wout only — so it is skipped entirely.
// ---------------------------------------------------------------------------
extern "C" void kernel_launch(void* const* d_in, const int* in_sizes, int n_in,
                              void* d_out, int out_size, void* d_ws, size_t ws_size,
                              hipStream_t stream) {
  const float* x_source = (const float*)d_in[0];
  const float* x_target = (const float*)d_in[1];
  const int* ei_st = (const int*)d_in[2];
  const int* ei_ts = (const int*)d_in[3];
  const float* Wl_st = (const float*)d_in[4];
  const float* Wr_st = (const float*)d_in[5];
  const float* b_st  = (const float*)d_in[6];
  const float* Wl_ts = (const float*)d_in[7];
  const float* Wr_ts = (const float*)d_in[8];
  const float* b_ts  = (const float*)d_in[9];
  const float* Wout  = (const float*)d_in[10];
  const float* bout  = (const float*)d_in[11];
  float* out = (float*)d_out;
  float* ws = (float*)d_ws;

  const size_t F = (size_t)NSRC * DIN;  // 12.8M floats
  const size_t need = (3 * F + NTGT + NSRC) * sizeof(float);
  if (ws_size < need) return;  // diagnostic guard: clean absmax-fail, not a GPU fault

  float* B0    = ws;
  float* B1    = ws + F;
  float* B2    = ws + 2 * F;
  float* cnt_t = ws + 3 * F;
  float* cnt_s = cnt_t + NTGT;

  const int WMAT = DIN * HID;  // per-layer weight stride
  const dim3 ggrid((NSRC + BM - 1) / BM, HID / BN);

  // ---------------- Layer 0 ----------------
  hipMemsetAsync(B0, 0, 2 * F * sizeof(float), stream);                 // B0,B1
  hipMemsetAsync(cnt_t, 0, (NTGT + NSRC) * sizeof(float), stream);
  scatter_kernel<<<NE / 4, 256, 0, stream>>>(x_source, ei_st, B0, cnt_t, NE); // m_t
  scatter_kernel<<<NE / 4, 256, 0, stream>>>(x_target, ei_ts, B1, cnt_s, NE); // m_s
  finalize_mean<<<NTGT / 4, 256, 0, stream>>>(B0, cnt_t, NTGT);
  finalize_mean<<<NSRC / 4, 256, 0, stream>>>(B1, cnt_s, NSRC);

  // new_t = leaky(m_t @ Wl_st[0] + b_st[0] + x_t @ Wr_st[0]) -> B2
  gemm_dual<<<ggrid, 256, 0, stream>>>(B0, x_target, Wl_st, Wr_st, b_st, B2, NTGT);
  // new_s = leaky(m_s @ Wl_ts[0] + b_ts[0] + x_s @ Wr_ts[0]) -> B0 (m_t consumed)
  gemm_dual<<<ggrid, 256, 0, stream>>>(B1, x_source, Wl_ts, Wr_ts, b_ts, B0, NSRC);

  {
    uint64_t fks = FOLD[0];  // x_s layer 0
    uint64_t fkt = FOLD[1];  // x_t layer 0
    dropout_kernel<<<(int)(F / 4 / 256), 256, 0, stream>>>(
        B0, (uint32_t)(fks >> 32), (uint32_t)fks, (int)(F / 4));
    dropout_kernel<<<(int)(F / 4 / 256), 256, 0, stream>>>(
        B2, (uint32_t)(fkt >> 32), (uint32_t)fkt, (int)(F / 4));
  }

  // ---------------- Layer 1 (source side only; target side is dead) --------
  hipMemsetAsync(B1, 0, F * sizeof(float), stream);
  hipMemsetAsync(cnt_s, 0, NSRC * sizeof(float), stream);
  scatter_kernel<<<NE / 4, 256, 0, stream>>>(B2, ei_ts, B1, cnt_s, NE);  // m_s from x_t(1)
  finalize_mean<<<NSRC / 4, 256, 0, stream>>>(B1, cnt_s, NSRC);

  // new_s = leaky(m_s @ Wl_ts[1] + b_ts[1] + x_s(1) @ Wr_ts[1]) -> B2 (x_t(1) consumed)
  gemm_dual<<<ggrid, 256, 0, stream>>>(B1, B0, Wl_ts + WMAT, Wr_ts + WMAT,
                                       b_ts + HID, B2, NSRC);
  {
    uint64_t fks = FOLD[2];  // x_s layer 1
    dropout_kernel<<<(int)(F / 4 / 256), 256, 0, stream>>>(
        B2, (uint32_t)(fks >> 32), (uint32_t)fks, (int)(F / 4));
  }

  out_gemm<<<(NSRC + 15) / 16, 256, 0, stream>>>(B2, Wout, bout, out, NSRC);
}

// Round 3
// 1233.843 us; speedup vs baseline: 3.3222x; 3.3222x over previous
//
#include <hip/hip_runtime.h>
#include <stdint.h>

// Problem constants (fixed by reference)
#define NSRC 50000
#define NTGT 50000
#define NE   320000
#define DIN  256
#define HID  256
#define DOUT 16

// ---------------------------------------------------------------------------
// Threefry-2x32 (exact JAX implementation: 20 rounds, 5 key injections)
// ---------------------------------------------------------------------------
__host__ __device__ constexpr uint64_t tf2x32(uint32_t k0, uint32_t k1,
                                              uint32_t x0, uint32_t x1) {
  uint32_t ks2 = k0 ^ k1 ^ 0x1BD11BDAu;
  x0 += k0; x1 += k1;
#define TF_ROT(x, r) (((x) << (r)) | ((x) >> (32 - (r))))
#define TF_RND(r) { x0 += x1; x1 = TF_ROT(x1, r) ^ x0; }
  TF_RND(13) TF_RND(15) TF_RND(26) TF_RND(6)
  x0 += k1;  x1 += ks2 + 1u;
  TF_RND(17) TF_RND(29) TF_RND(16) TF_RND(24)
  x0 += ks2; x1 += k0 + 2u;
  TF_RND(13) TF_RND(15) TF_RND(26) TF_RND(6)
  x0 += k0;  x1 += k1 + 3u;
  TF_RND(17) TF_RND(29) TF_RND(16) TF_RND(24)
  x0 += k1;  x1 += ks2 + 4u;
  TF_RND(13) TF_RND(15) TF_RND(26) TF_RND(6)
  x0 += ks2; x1 += k0 + 5u;
#undef TF_RND
#undef TF_ROT
  return (uint64_t(x0) << 32) | uint64_t(x1);
}

// fold_in(key(42), i) == threefry((0,42), (0,i)) -> new key (k0=out0, k1=out1)
constexpr uint64_t FOLD[4] = {
  tf2x32(0u, 42u, 0u, 0u),
  tf2x32(0u, 42u, 0u, 1u),
  tf2x32(0u, 42u, 0u, 2u),
  tf2x32(0u, 42u, 0u, 3u),
};

// ---------------------------------------------------------------------------
// Dropout: JAX partitionable random_bits: bits[j] = out0^out1 of tf(key,(0,j))
// u = bitcast((bits>>9)|0x3f800000)-1 ; keep iff u < 0.9 ; x *= 1/0.9
// (verified passing in R2)
// ---------------------------------------------------------------------------
__global__ __launch_bounds__(256) void dropout_kernel(float* __restrict__ x,
                                                      uint32_t k0, uint32_t k1,
                                                      int n4) {
  int i = blockIdx.x * 256 + threadIdx.x;
  if (i >= n4) return;
  float4 v = ((float4*)x)[i];
  float* pv = &v.x;
  uint32_t j = uint32_t(i) * 4u;
#pragma unroll
  for (int t = 0; t < 4; ++t) {
    uint64_t r = tf2x32(k0, k1, 0u, j + uint32_t(t));
    uint32_t bits = uint32_t(r >> 32) ^ uint32_t(r);
    float u = __uint_as_float((bits >> 9) | 0x3f800000u) - 1.0f;
    pv[t] = (u < 0.9f) ? pv[t] * (1.0f / 0.9f) : 0.0f;
  }
  ((float4*)x)[i] = v;
}

// ---------------------------------------------------------------------------
// CSR build: histogram -> 1-block scan -> fill.  Edge list: ei[0..E)=neighbor
// (message source), ei[E..2E)=dst.  cur[] doubles as histogram & fill cursor.
// ---------------------------------------------------------------------------
__global__ __launch_bounds__(256) void csr_hist(const int* __restrict__ ei,
                                                int* __restrict__ cur, int nE) {
  int e = blockIdx.x * 256 + threadIdx.x;
  if (e < nE) atomicAdd(cur + ei[nE + e], 1);
}

// single block, 1024 threads: exclusive scan of cur[0..n) -> offs[0..n], and
// reset cur to 0 for the fill pass.
__global__ __launch_bounds__(1024) void csr_scan(const int* __restrict__ cnt,
                                                 int* __restrict__ offs,
                                                 int* __restrict__ cur, int n) {
  __shared__ int part[1024];
  int tid = threadIdx.x;
  const int chunk = (n + 1023) / 1024;
  int lo = tid * chunk, hi = min(lo + chunk, n);
  int s = 0;
  for (int i = lo; i < hi; ++i) s += cnt[i];
  part[tid] = s;
  __syncthreads();
  // Hillis-Steele inclusive scan over 1024 partials
  for (int d = 1; d < 1024; d <<= 1) {
    int v = (tid >= d) ? part[tid - d] : 0;
    __syncthreads();
    part[tid] += v;
    __syncthreads();
  }
  int run = (tid == 0) ? 0 : part[tid - 1];  // exclusive base for this chunk
  for (int i = lo; i < hi; ++i) {
    int c = cnt[i];
    offs[i] = run;
    cur[i] = 0;
    run += c;
  }
  if (tid == 1023) offs[n] = part[1023];
}

__global__ __launch_bounds__(256) void csr_fill(const int* __restrict__ ei,
                                                const int* __restrict__ offs,
                                                int* __restrict__ cur,
                                                int* __restrict__ adj, int nE) {
  int e = blockIdx.x * 256 + threadIdx.x;
  if (e >= nE) return;
  int dst = ei[nE + e];
  int pos = atomicAdd(cur + dst, 1);
  adj[offs[dst] + pos] = ei[e];
}

// ---------------------------------------------------------------------------
// Segment-mean via CSR gather: one wave per destination row.
// 64 lanes x float4 = 256 floats = full row; loop over neighbor rows.
// ---------------------------------------------------------------------------
__global__ __launch_bounds__(256) void gather_mean(const float* __restrict__ x,
                                                   const int* __restrict__ offs,
                                                   const int* __restrict__ adj,
                                                   float* __restrict__ m,
                                                   int nRows) {
  int row = blockIdx.x * 4 + (threadIdx.x >> 6);
  int lane = threadIdx.x & 63;
  if (row >= nRows) return;
  int start = offs[row], end = offs[row + 1];
  float4 acc = make_float4(0.f, 0.f, 0.f, 0.f);
  for (int e = start; e < end; ++e) {
    int s = adj[e];
    float4 v = *(const float4*)(x + (size_t)s * DIN + lane * 4);
    acc.x += v.x; acc.y += v.y; acc.z += v.z; acc.w += v.w;
  }
  float inv = 1.0f / fmaxf((float)(end - start), 1.0f);
  acc.x *= inv; acc.y *= inv; acc.z *= inv; acc.w *= inv;
  *(float4*)(m + (size_t)row * DIN + lane * 4) = acc;
}

// ---------------------------------------------------------------------------
// Fused dual GEMM: C = leaky( A1@W1 + A2@W2 + bias ), fp32, 64x64 tile, BK=32
// ---------------------------------------------------------------------------
#define BM 64
#define BN 64
#define BK 32

__global__ __launch_bounds__(256) void gemm_dual(const float* __restrict__ A1,
                                                 const float* __restrict__ A2,
                                                 const float* __restrict__ W1,
                                                 const float* __restrict__ W2,
                                                 const float* __restrict__ bias,
                                                 float* __restrict__ C, int M) {
  __shared__ float sA[BK][BM + 4];
  __shared__ float sB[BK][BN];
  int tid = threadIdx.x;
  int mbase = blockIdx.x * BM;
  int nbase = blockIdx.y * BN;
  int tm = tid >> 4;
  int tn = tid & 15;
  float acc[4][4] = {};

  int la_c = tid & 31;
  int la_r = tid >> 5;
  int lb_r = tid >> 4;
  int lb_c = (tid & 15) * 4;

  for (int phase = 0; phase < 2; ++phase) {
    const float* A = phase ? A2 : A1;
    const float* W = phase ? W2 : W1;
    for (int kt = 0; kt < DIN; kt += BK) {
#pragma unroll
      for (int rr = 0; rr < BM; rr += 8) {
        int row = mbase + rr + la_r;
        row = row < M ? row : M - 1;
        sA[la_c][rr + la_r] = A[(size_t)row * DIN + kt + la_c];
      }
#pragma unroll
      for (int rr = 0; rr < BK; rr += 16) {
        const float4 w = *(const float4*)(W + (size_t)(kt + rr + lb_r) * HID + nbase + lb_c);
        *(float4*)&sB[rr + lb_r][lb_c] = w;
      }
      __syncthreads();
#pragma unroll
      for (int kk = 0; kk < BK; ++kk) {
        float4 a = *(float4*)&sA[kk][tm * 4];
        float4 b = *(float4*)&sB[kk][tn * 4];
        float av[4] = {a.x, a.y, a.z, a.w};
        float bv[4] = {b.x, b.y, b.z, b.w};
#pragma unroll
        for (int i = 0; i < 4; ++i)
#pragma unroll
          for (int j = 0; j < 4; ++j) acc[i][j] += av[i] * bv[j];
      }
      __syncthreads();
    }
  }

  float4 bb = *(const float4*)(bias + nbase + tn * 4);
  float bv[4] = {bb.x, bb.y, bb.z, bb.w};
#pragma unroll
  for (int i = 0; i < 4; ++i) {
    int row = mbase + tm * 4 + i;
    if (row < M) {
      float4 o;
      float* ov = &o.x;
#pragma unroll
      for (int j = 0; j < 4; ++j) {
        float v = acc[i][j] + bv[j];
        ov[j] = v >= 0.0f ? v : 0.01f * v;
      }
      *(float4*)(C + (size_t)row * HID + nbase + tn * 4) = o;
    }
  }
}

// ---------------------------------------------------------------------------
// Final projection: [M,256] @ [256,16] + bout
// ---------------------------------------------------------------------------
__global__ __launch_bounds__(256) void out_gemm(const float* __restrict__ X,
                                                const float* __restrict__ Wout,
                                                const float* __restrict__ bout,
                                                float* __restrict__ C, int M) {
  __shared__ float sW[DIN * DOUT];
  int tid = threadIdx.x;
#pragma unroll
  for (int i = 0; i < (DIN * DOUT) / 256; ++i) sW[i * 256 + tid] = Wout[i * 256 + tid];
  __syncthreads();
  int r = tid >> 4;
  int c = tid & 15;
  int row = blockIdx.x * 16 + r;
  if (row >= M) return;
  float acc = bout[c];
  const float* xp = X + (size_t)row * DIN;
#pragma unroll 4
  for (int k = 0; k < DIN; k += 4) {
    float4 xv = *(const float4*)(xp + k);
    acc += xv.x * sW[(k + 0) * DOUT + c];
    acc += xv.y * sW[(k + 1) * DOUT + c];
    acc += xv.z * sW[(k + 2) * DOUT + c];
    acc += xv.w * sW[(k + 3) * DOUT + c];
  }
  C[(size_t)row * DOUT + c] = acc;
}

// ---------------------------------------------------------------------------
// Workspace: B0,B1,B2 [F floats each] + CSR ints.  need ~157 MB (<R2-proven
// ws_size >= 154 MB; R1 proved >= 307 MB faults, so ws is likely 256 MB).
// Buffer lifetimes (single stream => launch order = exec order):
//   B0: m_t(L0) -> dead after gemm#1 -> x_s(1)
//   B1: m_s(L0) -> dead after gemm#2 -> m_s(L1)
//   B2: x_t(1)  -> dead after gather#3 -> x_s(2)
// Layer-1 target side is dead code (output = x_s @ Wout only).
// ---------------------------------------------------------------------------
extern "C" void kernel_launch(void* const* d_in, const int* in_sizes, int n_in,
                              void* d_out, int out_size, void* d_ws, size_t ws_size,
                              hipStream_t stream) {
  const float* x_source = (const float*)d_in[0];
  const float* x_target = (const float*)d_in[1];
  const int* ei_st = (const int*)d_in[2];
  const int* ei_ts = (const int*)d_in[3];
  const float* Wl_st = (const float*)d_in[4];
  const float* Wr_st = (const float*)d_in[5];
  const float* b_st  = (const float*)d_in[6];
  const float* Wl_ts = (const float*)d_in[7];
  const float* Wr_ts = (const float*)d_in[8];
  const float* b_ts  = (const float*)d_in[9];
  const float* Wout  = (const float*)d_in[10];
  const float* bout  = (const float*)d_in[11];
  float* out = (float*)d_out;
  float* ws = (float*)d_ws;

  const size_t F = (size_t)NSRC * DIN;  // 12.8M floats
  const size_t intCount = (NTGT + 1) + (NSRC + 1) + 2 * NE + NSRC;
  const size_t need = 3 * F * sizeof(float) + intCount * sizeof(int);
  if (ws_size < need) return;  // clean fail instead of GPU fault

  float* B0 = ws;
  float* B1 = ws + F;
  float* B2 = ws + 2 * F;
  int* ip      = (int*)(ws + 3 * F);
  int* offs_st = ip;                   // [NTGT+1]
  int* offs_ts = offs_st + NTGT + 1;   // [NSRC+1]
  int* adj_st  = offs_ts + NSRC + 1;   // [NE]
  int* adj_ts  = adj_st + NE;          // [NE]
  int* cur     = adj_ts + NE;          // [max(NTGT,NSRC)]

  const int WMAT = DIN * HID;
  const dim3 ggrid((NSRC + BM - 1) / BM, HID / BN);
  const int EB = (NE + 255) / 256;

  // ---- Build both CSRs (edge structure is layer-invariant) ----
  hipMemsetAsync(cur, 0, NTGT * sizeof(int), stream);
  csr_hist<<<EB, 256, 0, stream>>>(ei_st, cur, NE);
  csr_scan<<<1, 1024, 0, stream>>>(cur, offs_st, cur, NTGT);
  csr_fill<<<EB, 256, 0, stream>>>(ei_st, offs_st, cur, adj_st, NE);

  hipMemsetAsync(cur, 0, NSRC * sizeof(int), stream);
  csr_hist<<<EB, 256, 0, stream>>>(ei_ts, cur, NE);
  csr_scan<<<1, 1024, 0, stream>>>(cur, offs_ts, cur, NSRC);
  csr_fill<<<EB, 256, 0, stream>>>(ei_ts, offs_ts, cur, adj_ts, NE);

  // ---------------- Layer 0 ----------------
  gather_mean<<<NTGT / 4, 256, 0, stream>>>(x_source, offs_st, adj_st, B0, NTGT);
  gather_mean<<<NSRC / 4, 256, 0, stream>>>(x_target, offs_ts, adj_ts, B1, NSRC);

  gemm_dual<<<ggrid, 256, 0, stream>>>(B0, x_target, Wl_st, Wr_st, b_st, B2, NTGT);
  gemm_dual<<<ggrid, 256, 0, stream>>>(B1, x_source, Wl_ts, Wr_ts, b_ts, B0, NSRC);

  {
    uint64_t fks = FOLD[0], fkt = FOLD[1];
    dropout_kernel<<<(int)(F / 4 / 256), 256, 0, stream>>>(
        B0, (uint32_t)(fks >> 32), (uint32_t)fks, (int)(F / 4));
    dropout_kernel<<<(int)(F / 4 / 256), 256, 0, stream>>>(
        B2, (uint32_t)(fkt >> 32), (uint32_t)fkt, (int)(F / 4));
  }

  // ---------------- Layer 1 (source side only) ----------------
  gather_mean<<<NSRC / 4, 256, 0, stream>>>(B2, offs_ts, adj_ts, B1, NSRC);
  gemm_dual<<<ggrid, 256, 0, stream>>>(B1, B0, Wl_ts + WMAT, Wr_ts + WMAT,
                                       b_ts + HID, B2, NSRC);
  {
    uint64_t fks = FOLD[2];
    dropout_kernel<<<(int)(F / 4 / 256), 256, 0, stream>>>(
        B2, (uint32_t)(fks >> 32), (uint32_t)fks, (int)(F / 4));
  }

  out_gemm<<<(NSRC + 15) / 16, 256, 0, stream>>>(B2, Wout, bout, out, NSRC);
}

// Round 5
// 819.561 us; speedup vs baseline: 5.0015x; 1.5055x over previous
//
#include <hip/hip_runtime.h>
#include <stdint.h>

// Problem constants (fixed by reference)
#define NSRC 50000
#define NTGT 50000
#define NE   320000
#define DIN  256
#define HID  256
#define DOUT 16

typedef __attribute__((ext_vector_type(8))) short bf16x8;
typedef __attribute__((ext_vector_type(4))) float f32x4;

// ---------------------------------------------------------------------------
// bf16 <-> f32 (RNE, matches HW/XLA rounding)
// ---------------------------------------------------------------------------
__device__ inline ushort f2b(float f) {
  uint32_t u = __float_as_uint(f);
  return (ushort)((u + 0x7FFFu + ((u >> 16) & 1u)) >> 16);
}
__device__ inline float b2f(ushort h) { return __uint_as_float(((uint32_t)h) << 16); }

// ---------------------------------------------------------------------------
// Threefry-2x32 (exact JAX: 20 rounds, 5 key injections) — verified R2
// ---------------------------------------------------------------------------
__host__ __device__ constexpr uint64_t tf2x32(uint32_t k0, uint32_t k1,
                                              uint32_t x0, uint32_t x1) {
  uint32_t ks2 = k0 ^ k1 ^ 0x1BD11BDAu;
  x0 += k0; x1 += k1;
#define TF_ROT(x, r) (((x) << (r)) | ((x) >> (32 - (r))))
#define TF_RND(r) { x0 += x1; x1 = TF_ROT(x1, r) ^ x0; }
  TF_RND(13) TF_RND(15) TF_RND(26) TF_RND(6)
  x0 += k1;  x1 += ks2 + 1u;
  TF_RND(17) TF_RND(29) TF_RND(16) TF_RND(24)
  x0 += ks2; x1 += k0 + 2u;
  TF_RND(13) TF_RND(15) TF_RND(26) TF_RND(6)
  x0 += k0;  x1 += k1 + 3u;
  TF_RND(17) TF_RND(29) TF_RND(16) TF_RND(24)
  x0 += k1;  x1 += ks2 + 4u;
  TF_RND(13) TF_RND(15) TF_RND(26) TF_RND(6)
  x0 += ks2; x1 += k0 + 5u;
#undef TF_RND
#undef TF_ROT
  return (uint64_t(x0) << 32) | uint64_t(x1);
}

constexpr uint64_t FOLD[4] = {
  tf2x32(0u, 42u, 0u, 0u),
  tf2x32(0u, 42u, 0u, 1u),
  tf2x32(0u, 42u, 0u, 2u),
  tf2x32(0u, 42u, 0u, 3u),
};

// dropout p=0.1, partitionable threefry bits = out0^out1 of tf(key,(0,j))
__device__ inline float drop(float v, uint32_t k0, uint32_t k1, uint32_t j) {
  uint64_t r = tf2x32(k0, k1, 0u, j);
  uint32_t bits = uint32_t(r >> 32) ^ uint32_t(r);
  float u = __uint_as_float((bits >> 9) | 0x3f800000u) - 1.0f;
  return (u < 0.9f) ? v * (1.0f / 0.9f) : 0.0f;
}

// ---------------------------------------------------------------------------
// Conversions
// ---------------------------------------------------------------------------
__global__ __launch_bounds__(256) void cvt_f32_bf16(const float* __restrict__ in,
                                                    ushort* __restrict__ out, int n4) {
  int i = blockIdx.x * 256 + threadIdx.x;
  if (i >= n4) return;
  float4 v = ((const float4*)in)[i];
  ushort4 o;
  o.x = f2b(v.x); o.y = f2b(v.y); o.z = f2b(v.z); o.w = f2b(v.w);
  ((ushort4*)out)[i] = o;
}

// W fp32 [256 k][256 n] -> Wt bf16 [256 n][256 k]; grid 16 (4x4 tiles of 64)
__global__ __launch_bounds__(256) void wcvt_t(const float* __restrict__ W,
                                              ushort* __restrict__ Wt) {
  __shared__ ushort tile[64][65];
  int t = threadIdx.x;
  int ktile = blockIdx.x >> 2, ntile = blockIdx.x & 3;
#pragma unroll
  for (int rep = 0; rep < 16; ++rep) {
    int lin = rep * 256 + t;
    int kk = lin >> 6, nn = lin & 63;
    tile[nn][kk] = f2b(W[(size_t)(ktile * 64 + kk) * 256 + ntile * 64 + nn]);
  }
  __syncthreads();
#pragma unroll
  for (int rep = 0; rep < 16; ++rep) {
    int lin = rep * 256 + t;
    int nn = lin >> 6, kk = lin & 63;
    Wt[(size_t)(ntile * 64 + nn) * 256 + ktile * 64 + kk] = tile[nn][kk];
  }
}

// ---------------------------------------------------------------------------
// CSR build (verified R3)
// ---------------------------------------------------------------------------
__global__ __launch_bounds__(256) void csr_hist(const int* __restrict__ ei,
                                                int* __restrict__ cur, int nE) {
  int e = blockIdx.x * 256 + threadIdx.x;
  if (e < nE) atomicAdd(cur + ei[nE + e], 1);
}

__global__ __launch_bounds__(1024) void csr_scan(const int* __restrict__ cnt,
                                                 int* __restrict__ offs,
                                                 int* __restrict__ cur, int n) {
  __shared__ int part[1024];
  int tid = threadIdx.x;
  const int chunk = (n + 1023) / 1024;
  int lo = tid * chunk, hi = min(lo + chunk, n);
  int s = 0;
  for (int i = lo; i < hi; ++i) s += cnt[i];
  part[tid] = s;
  __syncthreads();
  for (int d = 1; d < 1024; d <<= 1) {
    int v = (tid >= d) ? part[tid - d] : 0;
    __syncthreads();
    part[tid] += v;
    __syncthreads();
  }
  int run = (tid == 0) ? 0 : part[tid - 1];
  for (int i = lo; i < hi; ++i) {
    int c = cnt[i];
    offs[i] = run;
    cur[i] = 0;
    run += c;
  }
  if (tid == 1023) offs[n] = part[1023];
}

__global__ __launch_bounds__(256) void csr_fill(const int* __restrict__ ei,
                                                const int* __restrict__ offs,
                                                int* __restrict__ cur,
                                                int* __restrict__ adj, int nE) {
  int e = blockIdx.x * 256 + threadIdx.x;
  if (e >= nE) return;
  int dst = ei[nE + e];
  int pos = atomicAdd(cur + dst, 1);
  adj[offs[dst] + pos] = ei[e];
}

// ---------------------------------------------------------------------------
// Segment-mean gather, bf16 in/out, fp32 accumulate. One wave per row.
// ---------------------------------------------------------------------------
__global__ __launch_bounds__(256) void gather_mean_h(const ushort* __restrict__ x,
                                                     const int* __restrict__ offs,
                                                     const int* __restrict__ adj,
                                                     ushort* __restrict__ m,
                                                     int nRows) {
  int row = blockIdx.x * 4 + (threadIdx.x >> 6);
  int lane = threadIdx.x & 63;
  if (row >= nRows) return;
  int start = offs[row], end = offs[row + 1];
  float a0 = 0.f, a1 = 0.f, a2 = 0.f, a3 = 0.f;
  for (int e = start; e < end; ++e) {
    int s = adj[e];
    ushort4 v = *(const ushort4*)(x + (size_t)s * DIN + lane * 4);
    a0 += b2f(v.x); a1 += b2f(v.y); a2 += b2f(v.z); a3 += b2f(v.w);
  }
  float inv = 1.0f / fmaxf((float)(end - start), 1.0f);
  ushort4 o;
  o.x = f2b(a0 * inv); o.y = f2b(a1 * inv); o.z = f2b(a2 * inv); o.w = f2b(a3 * inv);
  *(ushort4*)(m + (size_t)row * DIN + lane * 4) = o;
}

// ---------------------------------------------------------------------------
// MFMA dual GEMM: C = dropout(leaky(A1@W1 + A2@W2 + bias))  [bf16 in/out]
// Tile: 64 rows x 256 cols (full N -> A read once). BK=32, 16x16x32 bf16 MFMA.
// 4 waves; wave w owns cols [w*64, w*64+64): 4x4 tiles, fp32 acc.
// R4 BUG FIX: sB staging now writes the FULL 32-short k-chunk per row
// (w?q[0..3]); R4 wrote only 16 shorts -> q=2,3 fragments read uninitialized
// LDS -> NaN.  sA was already complete (256 thr x 8 = 64 rows x 32).
// Fragment layouts (m89-verified): A[m=lane&15][k=q*8+j]; B[n=lane&15][k=q*8+j]
// (B pre-transposed to [n][k]); C/D: col=lane&15, row=q*4+reg.
// ---------------------------------------------------------------------------
#define GBM 64
#define LDA 40
#define LDB 40

__global__ __launch_bounds__(256) void gemm_dual_mfma(
    const ushort* __restrict__ A1, const ushort* __restrict__ A2,
    const ushort* __restrict__ W1t, const ushort* __restrict__ W2t,
    const float* __restrict__ bias, ushort* __restrict__ C, int M,
    uint32_t k0, uint32_t k1) {
  __shared__ ushort sA[2][GBM * LDA];
  __shared__ ushort sB[2][HID * LDB];
  const int tid = threadIdx.x;
  const int wave = tid >> 6, lane = tid & 63;
  const int q = lane >> 4, r = lane & 15;
  const int mbase = blockIdx.x * GBM;

  f32x4 acc[4][4] = {};

  const int arow = tid >> 2;        // 0..63
  const int akc = (tid & 3) * 8;    // 0,8,16,24
  const int agrow = min(mbase + arow, M - 1);
  const ushort* a1p = A1 + (size_t)agrow * DIN + akc;
  const ushort* a2p = A2 + (size_t)agrow * DIN + akc;
  const ushort* w1p = W1t + (size_t)tid * DIN;
  const ushort* w2p = W2t + (size_t)tid * DIN;

  for (int kt = 0; kt < DIN; kt += 32) {
    __syncthreads();
    *(uint4*)&sA[0][arow * LDA + akc] = *(const uint4*)(a1p + kt);
    *(uint4*)&sA[1][arow * LDA + akc] = *(const uint4*)(a2p + kt);
    const uint4* w1q = (const uint4*)(w1p + kt);
    const uint4* w2q = (const uint4*)(w2p + kt);
#pragma unroll
    for (int c = 0; c < 4; ++c) {
      *(uint4*)&sB[0][tid * LDB + c * 8] = w1q[c];
      *(uint4*)&sB[1][tid * LDB + c * 8] = w2q[c];
    }
    __syncthreads();
#pragma unroll
    for (int ph = 0; ph < 2; ++ph) {
      bf16x8 af[4], bfr[4];
#pragma unroll
      for (int i = 0; i < 4; ++i)
        af[i] = *(const bf16x8*)&sA[ph][(i * 16 + r) * LDA + q * 8];
#pragma unroll
      for (int j = 0; j < 4; ++j)
        bfr[j] = *(const bf16x8*)&sB[ph][(wave * 64 + j * 16 + r) * LDB + q * 8];
#pragma unroll
      for (int i = 0; i < 4; ++i)
#pragma unroll
        for (int j = 0; j < 4; ++j)
          acc[i][j] = __builtin_amdgcn_mfma_f32_16x16x32_bf16(af[i], bfr[j],
                                                              acc[i][j], 0, 0, 0);
    }
  }

  // Epilogue: bias + leaky + dropout + bf16 store
  float bj[4];
#pragma unroll
  for (int j = 0; j < 4; ++j) bj[j] = bias[wave * 64 + j * 16 + r];
#pragma unroll
  for (int i = 0; i < 4; ++i) {
#pragma unroll
    for (int e = 0; e < 4; ++e) {
      int rowg = mbase + i * 16 + q * 4 + e;
      if (rowg >= M) continue;
#pragma unroll
      for (int j = 0; j < 4; ++j) {
        int colg = wave * 64 + j * 16 + r;
        float v = acc[i][j][e] + bj[j];
        v = v >= 0.0f ? v : 0.01f * v;
        v = drop(v, k0, k1, (uint32_t)rowg * 256u + (uint32_t)colg);
        C[(size_t)rowg * HID + colg] = f2b(v);
      }
    }
  }
}

// ---------------------------------------------------------------------------
// Final projection: [M,256] bf16 @ [256,16] fp32 + bout -> fp32
// ---------------------------------------------------------------------------
__global__ __launch_bounds__(256) void out_gemm_h(const ushort* __restrict__ X,
                                                  const float* __restrict__ Wout,
                                                  const float* __restrict__ bout,
                                                  float* __restrict__ C, int M) {
  __shared__ float sW[DIN * DOUT];
  int tid = threadIdx.x;
#pragma unroll
  for (int i = 0; i < (DIN * DOUT) / 256; ++i) sW[i * 256 + tid] = Wout[i * 256 + tid];
  __syncthreads();
  int rr = tid >> 4, c = tid & 15;
  int row = blockIdx.x * 16 + rr;
  if (row >= M) return;
  float acc = bout[c];
  const ushort* xp = X + (size_t)row * DIN;
  for (int k = 0; k < DIN; k += 8) {
    uint4 u = *(const uint4*)(xp + k);
    const ushort* us = (const ushort*)&u;
#pragma unroll
    for (int t = 0; t < 8; ++t) acc += b2f(us[t]) * sW[(k + t) * DOUT + c];
  }
  C[(size_t)row * DOUT + c] = acc;
}

// ---------------------------------------------------------------------------
// Workspace (~132 MB < 154 MB proven safe):
//   xs0h, xt0h [F bf16]  : converted inputs
//   B0h,B1h,B2h [F bf16] : activations (lifetime-overlapped, single stream)
//   wt[6]  [65536 bf16]  : transposed bf16 weights
//   CSR ints
// Layer-1 target side is dead code (output = x_s @ Wout only).
// ---------------------------------------------------------------------------
extern "C" void kernel_launch(void* const* d_in, const int* in_sizes, int n_in,
                              void* d_out, int out_size, void* d_ws, size_t ws_size,
                              hipStream_t stream) {
  const float* x_source = (const float*)d_in[0];
  const float* x_target = (const float*)d_in[1];
  const int* ei_st = (const int*)d_in[2];
  const int* ei_ts = (const int*)d_in[3];
  const float* Wl_st = (const float*)d_in[4];
  const float* Wr_st = (const float*)d_in[5];
  const float* b_st  = (const float*)d_in[6];
  const float* Wl_ts = (const float*)d_in[7];
  const float* Wr_ts = (const float*)d_in[8];
  const float* b_ts  = (const float*)d_in[9];
  const float* Wout  = (const float*)d_in[10];
  const float* bout  = (const float*)d_in[11];
  float* out = (float*)d_out;

  const size_t F = (size_t)NSRC * DIN;  // 12.8M elements
  const size_t WM = (size_t)DIN * HID;  // 65536
  const size_t intCount = (NTGT + 1) + (NSRC + 1) + 2 * NE + NSRC;
  const size_t need = (5 * F + 6 * WM) * sizeof(ushort) + intCount * sizeof(int);
  if (ws_size < need) return;

  ushort* xs0h = (ushort*)d_ws;
  ushort* xt0h = xs0h + F;
  ushort* B0h  = xt0h + F;
  ushort* B1h  = B0h + F;
  ushort* B2h  = B1h + F;
  ushort* wt0  = B2h + F;       // Wl_st[0]^T
  ushort* wt1  = wt0 + WM;      // Wr_st[0]^T
  ushort* wt2  = wt1 + WM;      // Wl_ts[0]^T
  ushort* wt3  = wt2 + WM;      // Wr_ts[0]^T
  ushort* wt4  = wt3 + WM;      // Wl_ts[1]^T
  ushort* wt5  = wt4 + WM;      // Wr_ts[1]^T
  int* ip      = (int*)(wt5 + WM);
  int* offs_st = ip;
  int* offs_ts = offs_st + NTGT + 1;
  int* adj_st  = offs_ts + NSRC + 1;
  int* adj_ts  = adj_st + NE;
  int* cur     = adj_ts + NE;

  const int EB = (NE + 255) / 256;
  const int GB = (NSRC + GBM - 1) / GBM;  // 782

  // ---- Convert inputs & weights to bf16 ----
  cvt_f32_bf16<<<(int)(F / 4 / 256), 256, 0, stream>>>(x_source, xs0h, (int)(F / 4));
  cvt_f32_bf16<<<(int)(F / 4 / 256), 256, 0, stream>>>(x_target, xt0h, (int)(F / 4));
  wcvt_t<<<16, 256, 0, stream>>>(Wl_st, wt0);
  wcvt_t<<<16, 256, 0, stream>>>(Wr_st, wt1);
  wcvt_t<<<16, 256, 0, stream>>>(Wl_ts, wt2);
  wcvt_t<<<16, 256, 0, stream>>>(Wr_ts, wt3);
  wcvt_t<<<16, 256, 0, stream>>>(Wl_ts + WM, wt4);
  wcvt_t<<<16, 256, 0, stream>>>(Wr_ts + WM, wt5);

  // ---- Build both CSRs ----
  hipMemsetAsync(cur, 0, NTGT * sizeof(int), stream);
  csr_hist<<<EB, 256, 0, stream>>>(ei_st, cur, NE);
  csr_scan<<<1, 1024, 0, stream>>>(cur, offs_st, cur, NTGT);
  csr_fill<<<EB, 256, 0, stream>>>(ei_st, offs_st, cur, adj_st, NE);

  hipMemsetAsync(cur, 0, NSRC * sizeof(int), stream);
  csr_hist<<<EB, 256, 0, stream>>>(ei_ts, cur, NE);
  csr_scan<<<1, 1024, 0, stream>>>(cur, offs_ts, cur, NSRC);
  csr_fill<<<EB, 256, 0, stream>>>(ei_ts, offs_ts, cur, adj_ts, NE);

  // ---------------- Layer 0 ----------------
  gather_mean_h<<<NTGT / 4, 256, 0, stream>>>(xs0h, offs_st, adj_st, B0h, NTGT);
  gather_mean_h<<<NSRC / 4, 256, 0, stream>>>(xt0h, offs_ts, adj_ts, B1h, NSRC);

  // new_t -> B2h (dropout key FOLD[1]);  new_s -> B0h (key FOLD[0])
  gemm_dual_mfma<<<GB, 256, 0, stream>>>(B0h, xt0h, wt0, wt1, b_st, B2h, NTGT,
                                         (uint32_t)(FOLD[1] >> 32), (uint32_t)FOLD[1]);
  gemm_dual_mfma<<<GB, 256, 0, stream>>>(B1h, xs0h, wt2, wt3, b_ts, B0h, NSRC,
                                         (uint32_t)(FOLD[0] >> 32), (uint32_t)FOLD[0]);

  // ---------------- Layer 1 (source side only) ----------------
  gather_mean_h<<<NSRC / 4, 256, 0, stream>>>(B2h, offs_ts, adj_ts, B1h, NSRC);
  gemm_dual_mfma<<<GB, 256, 0, stream>>>(B1h, B0h, wt4, wt5, b_ts + HID, B2h, NSRC,
                                         (uint32_t)(FOLD[2] >> 32), (uint32_t)FOLD[2]);

  out_gemm_h<<<(NSRC + 15) / 16, 256, 0, stream>>>(B2h, Wout, bout, out, NSRC);
}

// Round 6
// 579.313 us; speedup vs baseline: 7.0757x; 1.4147x over previous
//
#include <hip/hip_runtime.h>
#include <stdint.h>

// Problem constants (fixed by reference)
#define NSRC 50000
#define NTGT 50000
#define NE   320000
#define DIN  256
#define HID  256
#define DOUT 16

typedef __attribute__((ext_vector_type(8))) short bf16x8;
typedef __attribute__((ext_vector_type(4))) float f32x4;

// ---------------------------------------------------------------------------
// bf16 <-> f32 (RNE, matches HW/XLA rounding)
// ---------------------------------------------------------------------------
__device__ inline ushort f2b(float f) {
  uint32_t u = __float_as_uint(f);
  return (ushort)((u + 0x7FFFu + ((u >> 16) & 1u)) >> 16);
}
__device__ inline float b2f(ushort h) { return __uint_as_float(((uint32_t)h) << 16); }

// ---------------------------------------------------------------------------
// Threefry-2x32 (exact JAX: 20 rounds, 5 key injections) — verified R2
// ---------------------------------------------------------------------------
__host__ __device__ constexpr uint64_t tf2x32(uint32_t k0, uint32_t k1,
                                              uint32_t x0, uint32_t x1) {
  uint32_t ks2 = k0 ^ k1 ^ 0x1BD11BDAu;
  x0 += k0; x1 += k1;
#define TF_ROT(x, r) (((x) << (r)) | ((x) >> (32 - (r))))
#define TF_RND(r) { x0 += x1; x1 = TF_ROT(x1, r) ^ x0; }
  TF_RND(13) TF_RND(15) TF_RND(26) TF_RND(6)
  x0 += k1;  x1 += ks2 + 1u;
  TF_RND(17) TF_RND(29) TF_RND(16) TF_RND(24)
  x0 += ks2; x1 += k0 + 2u;
  TF_RND(13) TF_RND(15) TF_RND(26) TF_RND(6)
  x0 += k0;  x1 += k1 + 3u;
  TF_RND(17) TF_RND(29) TF_RND(16) TF_RND(24)
  x0 += k1;  x1 += ks2 + 4u;
  TF_RND(13) TF_RND(15) TF_RND(26) TF_RND(6)
  x0 += ks2; x1 += k0 + 5u;
#undef TF_RND
#undef TF_ROT
  return (uint64_t(x0) << 32) | uint64_t(x1);
}

constexpr uint64_t FOLD[4] = {
  tf2x32(0u, 42u, 0u, 0u),
  tf2x32(0u, 42u, 0u, 1u),
  tf2x32(0u, 42u, 0u, 2u),
  tf2x32(0u, 42u, 0u, 3u),
};

// dropout p=0.1, partitionable threefry bits = out0^out1 of tf(key,(0,j))
__device__ inline float drop(float v, uint32_t k0, uint32_t k1, uint32_t j) {
  uint64_t r = tf2x32(k0, k1, 0u, j);
  uint32_t bits = uint32_t(r >> 32) ^ uint32_t(r);
  float u = __uint_as_float((bits >> 9) | 0x3f800000u) - 1.0f;
  return (u < 0.9f) ? v * (1.0f / 0.9f) : 0.0f;
}

// ---------------------------------------------------------------------------
// Conversions (batched: 2 inputs in one launch; 6 weights in one launch)
// ---------------------------------------------------------------------------
__global__ __launch_bounds__(256) void cvt2_f32_bf16(const float* __restrict__ a,
                                                     const float* __restrict__ b,
                                                     ushort* __restrict__ oa,
                                                     ushort* __restrict__ ob,
                                                     int n4, int nbPer) {
  int blk = blockIdx.x;
  const float* in = blk < nbPer ? a : b;
  ushort* out = blk < nbPer ? oa : ob;
  int i = (blk % nbPer) * 256 + threadIdx.x;
  if (i >= n4) return;
  float4 v = ((const float4*)in)[i];
  ushort4 o;
  o.x = f2b(v.x); o.y = f2b(v.y); o.z = f2b(v.z); o.w = f2b(v.w);
  ((ushort4*)out)[i] = o;
}

struct W6 {
  const float* s[6];
  ushort* d[6];
};
// W fp32 [256 k][256 n] -> Wt bf16 [256 n][256 k]; 16 blocks per weight
__global__ __launch_bounds__(256) void wcvt_t6(W6 p) {
  __shared__ ushort tile[64][65];
  int w = blockIdx.x >> 4;
  const float* W = p.s[w];
  ushort* Wt = p.d[w];
  int t = threadIdx.x;
  int ktile = (blockIdx.x >> 2) & 3, ntile = blockIdx.x & 3;
#pragma unroll
  for (int rep = 0; rep < 16; ++rep) {
    int lin = rep * 256 + t;
    int kk = lin >> 6, nn = lin & 63;
    tile[nn][kk] = f2b(W[(size_t)(ktile * 64 + kk) * 256 + ntile * 64 + nn]);
  }
  __syncthreads();
#pragma unroll
  for (int rep = 0; rep < 16; ++rep) {
    int lin = rep * 256 + t;
    int nn = lin >> 6, kk = lin & 63;
    Wt[(size_t)(ntile * 64 + nn) * 256 + ktile * 64 + kk] = tile[nn][kk];
  }
}

// ---------------------------------------------------------------------------
// CSR build. Both relations processed in one grid per stage.
// R5 post-mortem: single-block csr_scan was 111 us (0.14% occupancy,
// latency-serialized). Replaced with two-level multi-block scan (~10 us).
// ---------------------------------------------------------------------------
__global__ __launch_bounds__(256) void csr_hist2(const int* __restrict__ ei_a,
                                                 const int* __restrict__ ei_b,
                                                 int* __restrict__ cur_a,
                                                 int* __restrict__ cur_b,
                                                 int nE, int nbPer) {
  int blk = blockIdx.x;
  const int* ei = blk < nbPer ? ei_a : ei_b;
  int* cur = blk < nbPer ? cur_a : cur_b;
  int e = (blk % nbPer) * 256 + threadIdx.x;
  if (e < nE) atomicAdd(cur + ei[nE + e], 1);
}

#define SB 1024
// stage 1: per-block sums of both histograms  (grid = 2*nbPer)
__global__ __launch_bounds__(SB) void scan_partial(const int* __restrict__ cur_a,
                                                   const int* __restrict__ cur_b,
                                                   int* __restrict__ bsum,
                                                   int n, int nbPer) {
  __shared__ int red[SB];
  int b = blockIdx.x;
  const int* cnt = b < nbPer ? cur_a : cur_b;
  int i = (b % nbPer) * SB + threadIdx.x;
  red[threadIdx.x] = (i < n) ? cnt[i] : 0;
  __syncthreads();
  for (int d = SB / 2; d > 0; d >>= 1) {
    if (threadIdx.x < d) red[threadIdx.x] += red[threadIdx.x + d];
    __syncthreads();
  }
  if (threadIdx.x == 0) bsum[b] = red[0];
}

// stage 2: exclusive-scan the (<=64) block sums of each half; 1 block.
__global__ __launch_bounds__(128) void scan_base(int* __restrict__ bsum, int nbPer) {
  __shared__ int buf[2][64];
  int half = threadIdx.x >> 6;
  int t = threadIdx.x & 63;
  buf[half][t] = (t < nbPer) ? bsum[half * nbPer + t] : 0;
  __syncthreads();
  for (int d = 1; d < 64; d <<= 1) {
    int v = (t >= d) ? buf[half][t - d] : 0;
    __syncthreads();
    buf[half][t] += v;
    __syncthreads();
  }
  if (t < nbPer) bsum[half * nbPer + t] = (t == 0) ? 0 : buf[half][t - 1];
}

// stage 3: block-local exclusive scan + base -> offs; zero cur for fill pass.
__global__ __launch_bounds__(SB) void scan_final(int* __restrict__ cur_a,
                                                 int* __restrict__ cur_b,
                                                 int* __restrict__ offs_a,
                                                 int* __restrict__ offs_b,
                                                 const int* __restrict__ bsum,
                                                 int n, int nbPer) {
  __shared__ int part[SB];
  int b = blockIdx.x;
  bool first = b < nbPer;
  int* cur = first ? cur_a : cur_b;
  int* offs = first ? offs_a : offs_b;
  int i = (b % nbPer) * SB + threadIdx.x;
  int v = (i < n) ? cur[i] : 0;
  part[threadIdx.x] = v;
  __syncthreads();
  for (int d = 1; d < SB; d <<= 1) {
    int tv = (threadIdx.x >= d) ? part[threadIdx.x - d] : 0;
    __syncthreads();
    part[threadIdx.x] += tv;
    __syncthreads();
  }
  int excl = part[threadIdx.x] - v + bsum[b];
  if (i < n) {
    offs[i] = excl;
    cur[i] = 0;
  }
  if (i == n - 1) offs[n] = excl + v;
}

__global__ __launch_bounds__(256) void csr_fill2(const int* __restrict__ ei_a,
                                                 const int* __restrict__ ei_b,
                                                 const int* __restrict__ offs_a,
                                                 const int* __restrict__ offs_b,
                                                 int* __restrict__ cur_a,
                                                 int* __restrict__ cur_b,
                                                 int* __restrict__ adj_a,
                                                 int* __restrict__ adj_b,
                                                 int nE, int nbPer) {
  int blk = blockIdx.x;
  bool first = blk < nbPer;
  const int* ei = first ? ei_a : ei_b;
  const int* offs = first ? offs_a : offs_b;
  int* cur = first ? cur_a : cur_b;
  int* adj = first ? adj_a : adj_b;
  int e = (blk % nbPer) * 256 + threadIdx.x;
  if (e >= nE) return;
  int dst = ei[nE + e];
  int pos = atomicAdd(cur + dst, 1);
  adj[offs[dst] + pos] = ei[e];
}

// ---------------------------------------------------------------------------
// Segment-mean gather, bf16 in/out, fp32 accumulate. One wave per row.
// ---------------------------------------------------------------------------
__global__ __launch_bounds__(256) void gather_mean_h(const ushort* __restrict__ x,
                                                     const int* __restrict__ offs,
                                                     const int* __restrict__ adj,
                                                     ushort* __restrict__ m,
                                                     int nRows) {
  int row = blockIdx.x * 4 + (threadIdx.x >> 6);
  int lane = threadIdx.x & 63;
  if (row >= nRows) return;
  int start = offs[row], end = offs[row + 1];
  float a0 = 0.f, a1 = 0.f, a2 = 0.f, a3 = 0.f;
  for (int e = start; e < end; ++e) {
    int s = adj[e];
    ushort4 v = *(const ushort4*)(x + (size_t)s * DIN + lane * 4);
    a0 += b2f(v.x); a1 += b2f(v.y); a2 += b2f(v.z); a3 += b2f(v.w);
  }
  float inv = 1.0f / fmaxf((float)(end - start), 1.0f);
  ushort4 o;
  o.x = f2b(a0 * inv); o.y = f2b(a1 * inv); o.z = f2b(a2 * inv); o.w = f2b(a3 * inv);
  *(ushort4*)(m + (size_t)row * DIN + lane * 4) = o;
}

// ---------------------------------------------------------------------------
// MFMA dual GEMM: C = dropout(leaky(A1@W1 + A2@W2 + bias))  [bf16 in/out]
// Tile: 64 rows x 256 cols (full N -> A read once). BK=32, 16x16x32 bf16 MFMA.
// 4 waves; wave w owns cols [w*64, w*64+64): 4x4 tiles, fp32 acc.
// (verified R5; byte-identical here)
// ---------------------------------------------------------------------------
#define GBM 64
#define LDA 40
#define LDB 40

__global__ __launch_bounds__(256) void gemm_dual_mfma(
    const ushort* __restrict__ A1, const ushort* __restrict__ A2,
    const ushort* __restrict__ W1t, const ushort* __restrict__ W2t,
    const float* __restrict__ bias, ushort* __restrict__ C, int M,
    uint32_t k0, uint32_t k1) {
  __shared__ ushort sA[2][GBM * LDA];
  __shared__ ushort sB[2][HID * LDB];
  const int tid = threadIdx.x;
  const int wave = tid >> 6, lane = tid & 63;
  const int q = lane >> 4, r = lane & 15;
  const int mbase = blockIdx.x * GBM;

  f32x4 acc[4][4] = {};

  const int arow = tid >> 2;        // 0..63
  const int akc = (tid & 3) * 8;    // 0,8,16,24
  const int agrow = min(mbase + arow, M - 1);
  const ushort* a1p = A1 + (size_t)agrow * DIN + akc;
  const ushort* a2p = A2 + (size_t)agrow * DIN + akc;
  const ushort* w1p = W1t + (size_t)tid * DIN;
  const ushort* w2p = W2t + (size_t)tid * DIN;

  for (int kt = 0; kt < DIN; kt += 32) {
    __syncthreads();
    *(uint4*)&sA[0][arow * LDA + akc] = *(const uint4*)(a1p + kt);
    *(uint4*)&sA[1][arow * LDA + akc] = *(const uint4*)(a2p + kt);
    const uint4* w1q = (const uint4*)(w1p + kt);
    const uint4* w2q = (const uint4*)(w2p + kt);
#pragma unroll
    for (int c = 0; c < 4; ++c) {
      *(uint4*)&sB[0][tid * LDB + c * 8] = w1q[c];
      *(uint4*)&sB[1][tid * LDB + c * 8] = w2q[c];
    }
    __syncthreads();
#pragma unroll
    for (int ph = 0; ph < 2; ++ph) {
      bf16x8 af[4], bfr[4];
#pragma unroll
      for (int i = 0; i < 4; ++i)
        af[i] = *(const bf16x8*)&sA[ph][(i * 16 + r) * LDA + q * 8];
#pragma unroll
      for (int j = 0; j < 4; ++j)
        bfr[j] = *(const bf16x8*)&sB[ph][(wave * 64 + j * 16 + r) * LDB + q * 8];
#pragma unroll
      for (int i = 0; i < 4; ++i)
#pragma unroll
        for (int j = 0; j < 4; ++j)
          acc[i][j] = __builtin_amdgcn_mfma_f32_16x16x32_bf16(af[i], bfr[j],
                                                              acc[i][j], 0, 0, 0);
    }
  }

  // Epilogue: bias + leaky + dropout + bf16 store
  float bj[4];
#pragma unroll
  for (int j = 0; j < 4; ++j) bj[j] = bias[wave * 64 + j * 16 + r];
#pragma unroll
  for (int i = 0; i < 4; ++i) {
#pragma unroll
    for (int e = 0; e < 4; ++e) {
      int rowg = mbase + i * 16 + q * 4 + e;
      if (rowg >= M) continue;
#pragma unroll
      for (int j = 0; j < 4; ++j) {
        int colg = wave * 64 + j * 16 + r;
        float v = acc[i][j][e] + bj[j];
        v = v >= 0.0f ? v : 0.01f * v;
        v = drop(v, k0, k1, (uint32_t)rowg * 256u + (uint32_t)colg);
        C[(size_t)rowg * HID + colg] = f2b(v);
      }
    }
  }
}

// ---------------------------------------------------------------------------
// Final projection: [M,256] bf16 @ [256,16] fp32 + bout -> fp32
// ---------------------------------------------------------------------------
__global__ __launch_bounds__(256) void out_gemm_h(const ushort* __restrict__ X,
                                                  const float* __restrict__ Wout,
                                                  const float* __restrict__ bout,
                                                  float* __restrict__ C, int M) {
  __shared__ float sW[DIN * DOUT];
  int tid = threadIdx.x;
#pragma unroll
  for (int i = 0; i < (DIN * DOUT) / 256; ++i) sW[i * 256 + tid] = Wout[i * 256 + tid];
  __syncthreads();
  int rr = tid >> 4, c = tid & 15;
  int row = blockIdx.x * 16 + rr;
  if (row >= M) return;
  float acc = bout[c];
  const ushort* xp = X + (size_t)row * DIN;
  for (int k = 0; k < DIN; k += 8) {
    uint4 u = *(const uint4*)(xp + k);
    const ushort* us = (const ushort*)&u;
#pragma unroll
    for (int t = 0; t < 8; ++t) acc += b2f(us[t]) * sW[(k + t) * DOUT + c];
  }
  C[(size_t)row * DOUT + c] = acc;
}

// ---------------------------------------------------------------------------
// Workspace (~133 MB < 154 MB proven safe):
//   xs0h, xt0h [F bf16]; B0h,B1h,B2h [F bf16]; wt[6] [65536 bf16];
//   CSR ints: offs_st/offs_ts/adj_st/adj_ts + cur_t,cur_s (adjacent) + bsum
// ---------------------------------------------------------------------------
extern "C" void kernel_launch(void* const* d_in, const int* in_sizes, int n_in,
                              void* d_out, int out_size, void* d_ws, size_t ws_size,
                              hipStream_t stream) {
  const float* x_source = (const float*)d_in[0];
  const float* x_target = (const float*)d_in[1];
  const int* ei_st = (const int*)d_in[2];
  const int* ei_ts = (const int*)d_in[3];
  const float* Wl_st = (const float*)d_in[4];
  const float* Wr_st = (const float*)d_in[5];
  const float* b_st  = (const float*)d_in[6];
  const float* Wl_ts = (const float*)d_in[7];
  const float* Wr_ts = (const float*)d_in[8];
  const float* b_ts  = (const float*)d_in[9];
  const float* Wout  = (const float*)d_in[10];
  const float* bout  = (const float*)d_in[11];
  float* out = (float*)d_out;

  const size_t F = (size_t)NSRC * DIN;  // 12.8M elements
  const size_t WM = (size_t)DIN * HID;  // 65536
  const int nbScan = (NSRC + SB - 1) / SB;  // 49 (NSRC==NTGT)
  const size_t intCount = (NTGT + 1) + (NSRC + 1) + 2 * NE + NTGT + NSRC + 2 * nbScan;
  const size_t need = (5 * F + 6 * WM) * sizeof(ushort) + intCount * sizeof(int);
  if (ws_size < need) return;

  ushort* xs0h = (ushort*)d_ws;
  ushort* xt0h = xs0h + F;
  ushort* B0h  = xt0h + F;
  ushort* B1h  = B0h + F;
  ushort* B2h  = B1h + F;
  ushort* wt0  = B2h + F;       // Wl_st[0]^T
  ushort* wt1  = wt0 + WM;      // Wr_st[0]^T
  ushort* wt2  = wt1 + WM;      // Wl_ts[0]^T
  ushort* wt3  = wt2 + WM;      // Wr_ts[0]^T
  ushort* wt4  = wt3 + WM;      // Wl_ts[1]^T
  ushort* wt5  = wt4 + WM;      // Wr_ts[1]^T
  int* ip      = (int*)(wt5 + WM);
  int* offs_st = ip;
  int* offs_ts = offs_st + NTGT + 1;
  int* adj_st  = offs_ts + NSRC + 1;
  int* adj_ts  = adj_st + NE;
  int* cur_t   = adj_ts + NE;        // [NTGT] + [NSRC] adjacent for one memset
  int* cur_s   = cur_t + NTGT;
  int* bsum    = cur_s + NSRC;       // [2*nbScan]

  const int EB = (NE + 255) / 256;
  const int CB = (int)(F / 4 + 255) / 256;  // cvt blocks per input
  const int GB = (NSRC + GBM - 1) / GBM;    // 782

  // ---- Convert inputs & weights to bf16 (batched launches) ----
  cvt2_f32_bf16<<<2 * CB, 256, 0, stream>>>(x_source, x_target, xs0h, xt0h,
                                            (int)(F / 4), CB);
  W6 wb;
  wb.s[0] = Wl_st;      wb.d[0] = wt0;
  wb.s[1] = Wr_st;      wb.d[1] = wt1;
  wb.s[2] = Wl_ts;      wb.d[2] = wt2;
  wb.s[3] = Wr_ts;      wb.d[3] = wt3;
  wb.s[4] = Wl_ts + WM; wb.d[4] = wt4;
  wb.s[5] = Wr_ts + WM; wb.d[5] = wt5;
  wcvt_t6<<<96, 256, 0, stream>>>(wb);

  // ---- Build both CSRs concurrently ----
  hipMemsetAsync(cur_t, 0, (NTGT + NSRC) * sizeof(int), stream);
  csr_hist2<<<2 * EB, 256, 0, stream>>>(ei_st, ei_ts, cur_t, cur_s, NE, EB);
  scan_partial<<<2 * nbScan, SB, 0, stream>>>(cur_t, cur_s, bsum, NTGT, nbScan);
  scan_base<<<1, 128, 0, stream>>>(bsum, nbScan);
  scan_final<<<2 * nbScan, SB, 0, stream>>>(cur_t, cur_s, offs_st, offs_ts,
                                            bsum, NTGT, nbScan);
  csr_fill2<<<2 * EB, 256, 0, stream>>>(ei_st, ei_ts, offs_st, offs_ts,
                                        cur_t, cur_s, adj_st, adj_ts, NE, EB);

  // ---------------- Layer 0 ----------------
  gather_mean_h<<<NTGT / 4, 256, 0, stream>>>(xs0h, offs_st, adj_st, B0h, NTGT);
  gather_mean_h<<<NSRC / 4, 256, 0, stream>>>(xt0h, offs_ts, adj_ts, B1h, NSRC);

  // new_t -> B2h (dropout key FOLD[1]);  new_s -> B0h (key FOLD[0])
  gemm_dual_mfma<<<GB, 256, 0, stream>>>(B0h, xt0h, wt0, wt1, b_st, B2h, NTGT,
                                         (uint32_t)(FOLD[1] >> 32), (uint32_t)FOLD[1]);
  gemm_dual_mfma<<<GB, 256, 0, stream>>>(B1h, xs0h, wt2, wt3, b_ts, B0h, NSRC,
                                         (uint32_t)(FOLD[0] >> 32), (uint32_t)FOLD[0]);

  // ---------------- Layer 1 (source side only; target side dead) ----------
  gather_mean_h<<<NSRC / 4, 256, 0, stream>>>(B2h, offs_ts, adj_ts, B1h, NSRC);
  gemm_dual_mfma<<<GB, 256, 0, stream>>>(B1h, B0h, wt4, wt5, b_ts + HID, B2h, NSRC,
                                         (uint32_t)(FOLD[2] >> 32), (uint32_t)FOLD[2]);

  out_gemm_h<<<(NSRC + 15) / 16, 256, 0, stream>>>(B2h, Wout, bout, out, NSRC);
}

// Round 7
// 566.394 us; speedup vs baseline: 7.2371x; 1.0228x over previous
//
#include <hip/hip_runtime.h>
#include <stdint.h>

// Problem constants (fixed by reference)
#define NSRC 50000
#define NTGT 50000
#define NE   320000
#define DIN  256
#define HID  256
#define DOUT 16

typedef __attribute__((ext_vector_type(8))) short bf16x8;
typedef __attribute__((ext_vector_type(4))) float f32x4;

// ---------------------------------------------------------------------------
// bf16 <-> f32 (RNE, matches HW/XLA rounding)
// ---------------------------------------------------------------------------
__device__ inline ushort f2b(float f) {
  uint32_t u = __float_as_uint(f);
  return (ushort)((u + 0x7FFFu + ((u >> 16) & 1u)) >> 16);
}
__device__ inline float b2f(ushort h) { return __uint_as_float(((uint32_t)h) << 16); }

// ---------------------------------------------------------------------------
// Async global->LDS 16B copy. HW semantics: each lane of the wave deposits
// its 16 B at lds_base + lane*16; lds_base must be wave-uniform.
// ---------------------------------------------------------------------------
typedef __attribute__((address_space(3))) uint32_t lds_u32_t;
typedef const __attribute__((address_space(1))) uint32_t glb_u32_t;
__device__ __forceinline__ void ld_lds16(const ushort* g, ushort* lds) {
  __builtin_amdgcn_global_load_lds((glb_u32_t*)g, (lds_u32_t*)lds, 16, 0, 0);
}

// ---------------------------------------------------------------------------
// Threefry-2x32 (exact JAX: 20 rounds, 5 key injections) — verified R2
// ---------------------------------------------------------------------------
__host__ __device__ constexpr uint64_t tf2x32(uint32_t k0, uint32_t k1,
                                              uint32_t x0, uint32_t x1) {
  uint32_t ks2 = k0 ^ k1 ^ 0x1BD11BDAu;
  x0 += k0; x1 += k1;
#define TF_ROT(x, r) (((x) << (r)) | ((x) >> (32 - (r))))
#define TF_RND(r) { x0 += x1; x1 = TF_ROT(x1, r) ^ x0; }
  TF_RND(13) TF_RND(15) TF_RND(26) TF_RND(6)
  x0 += k1;  x1 += ks2 + 1u;
  TF_RND(17) TF_RND(29) TF_RND(16) TF_RND(24)
  x0 += ks2; x1 += k0 + 2u;
  TF_RND(13) TF_RND(15) TF_RND(26) TF_RND(6)
  x0 += k0;  x1 += k1 + 3u;
  TF_RND(17) TF_RND(29) TF_RND(16) TF_RND(24)
  x0 += k1;  x1 += ks2 + 4u;
  TF_RND(13) TF_RND(15) TF_RND(26) TF_RND(6)
  x0 += ks2; x1 += k0 + 5u;
#undef TF_RND
#undef TF_ROT
  return (uint64_t(x0) << 32) | uint64_t(x1);
}

constexpr uint64_t FOLD[4] = {
  tf2x32(0u, 42u, 0u, 0u),
  tf2x32(0u, 42u, 0u, 1u),
  tf2x32(0u, 42u, 0u, 2u),
  tf2x32(0u, 42u, 0u, 3u),
};

// ---------------------------------------------------------------------------
// Conversions (batched)
// ---------------------------------------------------------------------------
__global__ __launch_bounds__(256) void cvt2_f32_bf16(const float* __restrict__ a,
                                                     const float* __restrict__ b,
                                                     ushort* __restrict__ oa,
                                                     ushort* __restrict__ ob,
                                                     int n4, int nbPer) {
  int blk = blockIdx.x;
  const float* in = blk < nbPer ? a : b;
  ushort* out = blk < nbPer ? oa : ob;
  int i = (blk % nbPer) * 256 + threadIdx.x;
  if (i >= n4) return;
  float4 v = ((const float4*)in)[i];
  ushort4 o;
  o.x = f2b(v.x); o.y = f2b(v.y); o.z = f2b(v.z); o.w = f2b(v.w);
  ((ushort4*)out)[i] = o;
}

struct W6 {
  const float* s[6];
  ushort* d[6];
};
// W fp32 [256 k][256 n] -> Wt bf16 [256 n][256 k]; 16 blocks per weight
__global__ __launch_bounds__(256) void wcvt_t6(W6 p) {
  __shared__ ushort tile[64][65];
  int w = blockIdx.x >> 4;
  const float* W = p.s[w];
  ushort* Wt = p.d[w];
  int t = threadIdx.x;
  int ktile = (blockIdx.x >> 2) & 3, ntile = blockIdx.x & 3;
#pragma unroll
  for (int rep = 0; rep < 16; ++rep) {
    int lin = rep * 256 + t;
    int kk = lin >> 6, nn = lin & 63;
    tile[nn][kk] = f2b(W[(size_t)(ktile * 64 + kk) * 256 + ntile * 64 + nn]);
  }
  __syncthreads();
#pragma unroll
  for (int rep = 0; rep < 16; ++rep) {
    int lin = rep * 256 + t;
    int nn = lin >> 6, kk = lin & 63;
    Wt[(size_t)(ntile * 64 + nn) * 256 + ktile * 64 + kk] = tile[nn][kk];
  }
}

// ---------------------------------------------------------------------------
// CSR build (two-level scan, verified R6)
// ---------------------------------------------------------------------------
__global__ __launch_bounds__(256) void csr_hist2(const int* __restrict__ ei_a,
                                                 const int* __restrict__ ei_b,
                                                 int* __restrict__ cur_a,
                                                 int* __restrict__ cur_b,
                                                 int nE, int nbPer) {
  int blk = blockIdx.x;
  const int* ei = blk < nbPer ? ei_a : ei_b;
  int* cur = blk < nbPer ? cur_a : cur_b;
  int e = (blk % nbPer) * 256 + threadIdx.x;
  if (e < nE) atomicAdd(cur + ei[nE + e], 1);
}

#define SB 1024
__global__ __launch_bounds__(SB) void scan_partial(const int* __restrict__ cur_a,
                                                   const int* __restrict__ cur_b,
                                                   int* __restrict__ bsum,
                                                   int n, int nbPer) {
  __shared__ int red[SB];
  int b = blockIdx.x;
  const int* cnt = b < nbPer ? cur_a : cur_b;
  int i = (b % nbPer) * SB + threadIdx.x;
  red[threadIdx.x] = (i < n) ? cnt[i] : 0;
  __syncthreads();
  for (int d = SB / 2; d > 0; d >>= 1) {
    if (threadIdx.x < d) red[threadIdx.x] += red[threadIdx.x + d];
    __syncthreads();
  }
  if (threadIdx.x == 0) bsum[b] = red[0];
}

__global__ __launch_bounds__(128) void scan_base(int* __restrict__ bsum, int nbPer) {
  __shared__ int buf[2][64];
  int half = threadIdx.x >> 6;
  int t = threadIdx.x & 63;
  buf[half][t] = (t < nbPer) ? bsum[half * nbPer + t] : 0;
  __syncthreads();
  for (int d = 1; d < 64; d <<= 1) {
    int v = (t >= d) ? buf[half][t - d] : 0;
    __syncthreads();
    buf[half][t] += v;
    __syncthreads();
  }
  if (t < nbPer) bsum[half * nbPer + t] = (t == 0) ? 0 : buf[half][t - 1];
}

__global__ __launch_bounds__(SB) void scan_final(int* __restrict__ cur_a,
                                                 int* __restrict__ cur_b,
                                                 int* __restrict__ offs_a,
                                                 int* __restrict__ offs_b,
                                                 const int* __restrict__ bsum,
                                                 int n, int nbPer) {
  __shared__ int part[SB];
  int b = blockIdx.x;
  bool first = b < nbPer;
  int* cur = first ? cur_a : cur_b;
  int* offs = first ? offs_a : offs_b;
  int i = (b % nbPer) * SB + threadIdx.x;
  int v = (i < n) ? cur[i] : 0;
  part[threadIdx.x] = v;
  __syncthreads();
  for (int d = 1; d < SB; d <<= 1) {
    int tv = (threadIdx.x >= d) ? part[threadIdx.x - d] : 0;
    __syncthreads();
    part[threadIdx.x] += tv;
    __syncthreads();
  }
  int excl = part[threadIdx.x] - v + bsum[b];
  if (i < n) {
    offs[i] = excl;
    cur[i] = 0;
  }
  if (i == n - 1) offs[n] = excl + v;
}

__global__ __launch_bounds__(256) void csr_fill2(const int* __restrict__ ei_a,
                                                 const int* __restrict__ ei_b,
                                                 const int* __restrict__ offs_a,
                                                 const int* __restrict__ offs_b,
                                                 int* __restrict__ cur_a,
                                                 int* __restrict__ cur_b,
                                                 int* __restrict__ adj_a,
                                                 int* __restrict__ adj_b,
                                                 int nE, int nbPer) {
  int blk = blockIdx.x;
  bool first = blk < nbPer;
  const int* ei = first ? ei_a : ei_b;
  const int* offs = first ? offs_a : offs_b;
  int* cur = first ? cur_a : cur_b;
  int* adj = first ? adj_a : adj_b;
  int e = (blk % nbPer) * 256 + threadIdx.x;
  if (e >= nE) return;
  int dst = ei[nE + e];
  int pos = atomicAdd(cur + dst, 1);
  adj[offs[dst] + pos] = ei[e];
}

// ---------------------------------------------------------------------------
// Segment-mean gather, bf16 in/out, fp32 accumulate. One wave per row.
// ---------------------------------------------------------------------------
__global__ __launch_bounds__(256) void gather_mean_h(const ushort* __restrict__ x,
                                                     const int* __restrict__ offs,
                                                     const int* __restrict__ adj,
                                                     ushort* __restrict__ m,
                                                     int nRows) {
  int row = blockIdx.x * 4 + (threadIdx.x >> 6);
  int lane = threadIdx.x & 63;
  if (row >= nRows) return;
  int start = offs[row], end = offs[row + 1];
  float a0 = 0.f, a1 = 0.f, a2 = 0.f, a3 = 0.f;
  for (int e = start; e < end; ++e) {
    int s = adj[e];
    ushort4 v = *(const ushort4*)(x + (size_t)s * DIN + lane * 4);
    a0 += b2f(v.x); a1 += b2f(v.y); a2 += b2f(v.z); a3 += b2f(v.w);
  }
  float inv = 1.0f / fmaxf((float)(end - start), 1.0f);
  ushort4 o;
  o.x = f2b(a0 * inv); o.y = f2b(a1 * inv); o.z = f2b(a2 * inv); o.w = f2b(a3 * inv);
  *(ushort4*)(m + (size_t)row * DIN + lane * 4) = o;
}

// ---------------------------------------------------------------------------
// MFMA dual GEMM v2: C = dropout(leaky(A1@W1 + A2@W2 + bias))  [bf16 in/out]
// R6 post-mortem: stall-bound (MfmaUtil 6.4%, VALUBusy 37%, 3 blk/CU).
// Changes:
//  - async global_load_lds width=16 staging, unpadded LDS (lane*16 contiguous:
//    sA offset (tid>>2)*64+(tid&3)*16 == tid*16; sB instr c at c*4096+tid*16)
//  - LDS 51.2->40 KB => 4 blocks/CU
//  - threefry dropout decisions computed 8/k-iter between async-issue and the
//    drain barrier (hidden under load latency), packed in a 64-bit keep mask.
//    Integer keep test: 0.9f == 7549747*2^-23 exactly, so keep <=> bits>>9 < 7549747.
// Fragment layouts (m89-verified): A[m=lane&15][k=q*8+j]; B[n=lane&15][k=q*8+j]
// (B pre-transposed to [n][k]); C/D: col=lane&15, row=q*4+reg.
// ---------------------------------------------------------------------------
#define GBM 64

__global__ __launch_bounds__(256) void gemm_dual_mfma(
    const ushort* __restrict__ A1, const ushort* __restrict__ A2,
    const ushort* __restrict__ W1t, const ushort* __restrict__ W2t,
    const float* __restrict__ bias, ushort* __restrict__ C, int M,
    uint32_t k0, uint32_t k1) {
  __shared__ ushort sA[2][GBM * 32];    // 4 KB per buffer
  __shared__ ushort sB[2][HID * 32];    // 16 KB per buffer
  const int tid = threadIdx.x;
  const int wave = tid >> 6, lane = tid & 63;
  const int q = lane >> 4, r = lane & 15;
  const int mbase = blockIdx.x * GBM;

  f32x4 acc[4][4] = {};

  const int arow = tid >> 2;        // 0..63
  const int akc = (tid & 3) * 8;    // short offset 0,8,16,24
  const int agrow = min(mbase + arow, M - 1);
  const ushort* a1p = A1 + (size_t)agrow * DIN + akc;
  const ushort* a2p = A2 + (size_t)agrow * DIN + akc;
  // sB staging instruction c covers weight rows c*64 + arow
  const ushort* w1p[4];
  const ushort* w2p[4];
#pragma unroll
  for (int c = 0; c < 4; ++c) {
    w1p[c] = W1t + (size_t)(c * 64 + arow) * DIN + akc;
    w2p[c] = W2t + (size_t)(c * 64 + arow) * DIN + akc;
  }
  // wave-uniform LDS bases (lane*16 B appended by HW)
  ushort* ldsA0 = &sA[0][wave * 512];
  ushort* ldsA1 = &sA[1][wave * 512];

  uint32_t keepLo = 0, keepHi = 0;

#pragma unroll
  for (int t = 0; t < 8; ++t) {
    const int kt = t * 32;
    __syncthreads();  // prior iter's LDS reads done before DMA overwrites
    ld_lds16(a1p + kt, ldsA0);
    ld_lds16(a2p + kt, ldsA1);
#pragma unroll
    for (int c = 0; c < 4; ++c) {
      ld_lds16(w1p[c] + kt, &sB[0][c * 2048 + wave * 512]);
      ld_lds16(w2p[c] + kt, &sB[1][c * 2048 + wave * 512]);
    }
    // 8 dropout hashes (pure VALU) hidden under the 10 in-flight loads
#pragma unroll
    for (int h = 0; h < 8; ++h) {
      const int s = t * 8 + h;
      const int si = s >> 4, se = (s >> 2) & 3, sj = s & 3;
      uint32_t rowg = (uint32_t)(mbase + si * 16 + q * 4 + se);
      uint32_t colg = (uint32_t)(wave * 64 + sj * 16 + r);
      uint64_t rr = tf2x32(k0, k1, 0u, rowg * 256u + colg);
      uint32_t bits = (uint32_t)(rr >> 32) ^ (uint32_t)rr;
      uint32_t keep = ((bits >> 9) < 7549747u) ? 1u : 0u;
      if (s < 32) keepLo |= keep << s;
      else        keepHi |= keep << (s - 32);
    }
    __syncthreads();  // drains vmcnt(0): DMA complete
#pragma unroll
    for (int ph = 0; ph < 2; ++ph) {
      bf16x8 af[4], bfr[4];
#pragma unroll
      for (int i = 0; i < 4; ++i)
        af[i] = *(const bf16x8*)&sA[ph][(i * 16 + r) * 32 + q * 8];
#pragma unroll
      for (int j = 0; j < 4; ++j)
        bfr[j] = *(const bf16x8*)&sB[ph][(wave * 64 + j * 16 + r) * 32 + q * 8];
#pragma unroll
      for (int i = 0; i < 4; ++i)
#pragma unroll
        for (int j = 0; j < 4; ++j)
          acc[i][j] = __builtin_amdgcn_mfma_f32_16x16x32_bf16(af[i], bfr[j],
                                                              acc[i][j], 0, 0, 0);
    }
  }

  // Epilogue: bias + leaky + masked dropout scale + bf16 store
  float bj[4];
#pragma unroll
  for (int j = 0; j < 4; ++j) bj[j] = bias[wave * 64 + j * 16 + r];
#pragma unroll
  for (int i = 0; i < 4; ++i) {
#pragma unroll
    for (int e = 0; e < 4; ++e) {
      int rowg = mbase + i * 16 + q * 4 + e;
      if (rowg >= M) continue;
#pragma unroll
      for (int j = 0; j < 4; ++j) {
        const int s = i * 16 + e * 4 + j;
        int colg = wave * 64 + j * 16 + r;
        float v = acc[i][j][e] + bj[j];
        v = v >= 0.0f ? v : 0.01f * v;
        uint32_t keep = ((s < 32 ? keepLo >> s : keepHi >> (s - 32)) & 1u);
        v = keep ? v * (1.0f / 0.9f) : 0.0f;
        C[(size_t)rowg * HID + colg] = f2b(v);
      }
    }
  }
}

// ---------------------------------------------------------------------------
// Final projection: [M,256] bf16 @ [256,16] fp32 + bout -> fp32
// ---------------------------------------------------------------------------
__global__ __launch_bounds__(256) void out_gemm_h(const ushort* __restrict__ X,
                                                  const float* __restrict__ Wout,
                                                  const float* __restrict__ bout,
                                                  float* __restrict__ C, int M) {
  __shared__ float sW[DIN * DOUT];
  int tid = threadIdx.x;
#pragma unroll
  for (int i = 0; i < (DIN * DOUT) / 256; ++i) sW[i * 256 + tid] = Wout[i * 256 + tid];
  __syncthreads();
  int rr = tid >> 4, c = tid & 15;
  int row = blockIdx.x * 16 + rr;
  if (row >= M) return;
  float acc = bout[c];
  const ushort* xp = X + (size_t)row * DIN;
  for (int k = 0; k < DIN; k += 8) {
    uint4 u = *(const uint4*)(xp + k);
    const ushort* us = (const ushort*)&u;
#pragma unroll
    for (int t = 0; t < 8; ++t) acc += b2f(us[t]) * sW[(k + t) * DOUT + c];
  }
  C[(size_t)row * DOUT + c] = acc;
}

// ---------------------------------------------------------------------------
// Workspace (~133 MB < 154 MB proven safe)
// ---------------------------------------------------------------------------
extern "C" void kernel_launch(void* const* d_in, const int* in_sizes, int n_in,
                              void* d_out, int out_size, void* d_ws, size_t ws_size,
                              hipStream_t stream) {
  const float* x_source = (const float*)d_in[0];
  const float* x_target = (const float*)d_in[1];
  const int* ei_st = (const int*)d_in[2];
  const int* ei_ts = (const int*)d_in[3];
  const float* Wl_st = (const float*)d_in[4];
  const float* Wr_st = (const float*)d_in[5];
  const float* b_st  = (const float*)d_in[6];
  const float* Wl_ts = (const float*)d_in[7];
  const float* Wr_ts = (const float*)d_in[8];
  const float* b_ts  = (const float*)d_in[9];
  const float* Wout  = (const float*)d_in[10];
  const float* bout  = (const float*)d_in[11];
  float* out = (float*)d_out;

  const size_t F = (size_t)NSRC * DIN;  // 12.8M elements
  const size_t WM = (size_t)DIN * HID;  // 65536
  const int nbScan = (NSRC + SB - 1) / SB;  // 49 (NSRC==NTGT)
  const size_t intCount = (NTGT + 1) + (NSRC + 1) + 2 * NE + NTGT + NSRC + 2 * nbScan;
  const size_t need = (5 * F + 6 * WM) * sizeof(ushort) + intCount * sizeof(int);
  if (ws_size < need) return;

  ushort* xs0h = (ushort*)d_ws;
  ushort* xt0h = xs0h + F;
  ushort* B0h  = xt0h + F;
  ushort* B1h  = B0h + F;
  ushort* B2h  = B1h + F;
  ushort* wt0  = B2h + F;       // Wl_st[0]^T
  ushort* wt1  = wt0 + WM;      // Wr_st[0]^T
  ushort* wt2  = wt1 + WM;      // Wl_ts[0]^T
  ushort* wt3  = wt2 + WM;      // Wr_ts[0]^T
  ushort* wt4  = wt3 + WM;      // Wl_ts[1]^T
  ushort* wt5  = wt4 + WM;      // Wr_ts[1]^T
  int* ip      = (int*)(wt5 + WM);
  int* offs_st = ip;
  int* offs_ts = offs_st + NTGT + 1;
  int* adj_st  = offs_ts + NSRC + 1;
  int* adj_ts  = adj_st + NE;
  int* cur_t   = adj_ts + NE;        // [NTGT] + [NSRC] adjacent for one memset
  int* cur_s   = cur_t + NTGT;
  int* bsum    = cur_s + NSRC;       // [2*nbScan]

  const int EB = (NE + 255) / 256;
  const int CB = (int)(F / 4 + 255) / 256;  // cvt blocks per input
  const int GB = (NSRC + GBM - 1) / GBM;    // 782

  // ---- Convert inputs & weights to bf16 (batched launches) ----
  cvt2_f32_bf16<<<2 * CB, 256, 0, stream>>>(x_source, x_target, xs0h, xt0h,
                                            (int)(F / 4), CB);
  W6 wb;
  wb.s[0] = Wl_st;      wb.d[0] = wt0;
  wb.s[1] = Wr_st;      wb.d[1] = wt1;
  wb.s[2] = Wl_ts;      wb.d[2] = wt2;
  wb.s[3] = Wr_ts;      wb.d[3] = wt3;
  wb.s[4] = Wl_ts + WM; wb.d[4] = wt4;
  wb.s[5] = Wr_ts + WM; wb.d[5] = wt5;
  wcvt_t6<<<96, 256, 0, stream>>>(wb);

  // ---- Build both CSRs concurrently ----
  hipMemsetAsync(cur_t, 0, (NTGT + NSRC) * sizeof(int), stream);
  csr_hist2<<<2 * EB, 256, 0, stream>>>(ei_st, ei_ts, cur_t, cur_s, NE, EB);
  scan_partial<<<2 * nbScan, SB, 0, stream>>>(cur_t, cur_s, bsum, NTGT, nbScan);
  scan_base<<<1, 128, 0, stream>>>(bsum, nbScan);
  scan_final<<<2 * nbScan, SB, 0, stream>>>(cur_t, cur_s, offs_st, offs_ts,
                                            bsum, NTGT, nbScan);
  csr_fill2<<<2 * EB, 256, 0, stream>>>(ei_st, ei_ts, offs_st, offs_ts,
                                        cur_t, cur_s, adj_st, adj_ts, NE, EB);

  // ---------------- Layer 0 ----------------
  gather_mean_h<<<NTGT / 4, 256, 0, stream>>>(xs0h, offs_st, adj_st, B0h, NTGT);
  gather_mean_h<<<NSRC / 4, 256, 0, stream>>>(xt0h, offs_ts, adj_ts, B1h, NSRC);

  // new_t -> B2h (dropout key FOLD[1]);  new_s -> B0h (key FOLD[0])
  gemm_dual_mfma<<<GB, 256, 0, stream>>>(B0h, xt0h, wt0, wt1, b_st, B2h, NTGT,
                                         (uint32_t)(FOLD[1] >> 32), (uint32_t)FOLD[1]);
  gemm_dual_mfma<<<GB, 256, 0, stream>>>(B1h, xs0h, wt2, wt3, b_ts, B0h, NSRC,
                                         (uint32_t)(FOLD[0] >> 32), (uint32_t)FOLD[0]);

  // ---------------- Layer 1 (source side only; target side dead) ----------
  gather_mean_h<<<NSRC / 4, 256, 0, stream>>>(B2h, offs_ts, adj_ts, B1h, NSRC);
  gemm_dual_mfma<<<GB, 256, 0, stream>>>(B1h, B0h, wt4, wt5, b_ts + HID, B2h, NSRC,
                                         (uint32_t)(FOLD[2] >> 32), (uint32_t)FOLD[2]);

  out_gemm_h<<<(NSRC + 15) / 16, 256, 0, stream>>>(B2h, Wout, bout, out, NSRC);
}

// Round 8
// 516.372 us; speedup vs baseline: 7.9381x; 1.0969x over previous
//
#include <hip/hip_runtime.h>
#include <stdint.h>

// Problem constants (fixed by reference)
#define NSRC 50000
#define NTGT 50000
#define NE   320000
#define DIN  256
#define HID  256
#define DOUT 16

#define GBM 64
#define GBLK ((NSRC + GBM - 1) / GBM)      // 782 gemm blocks
#define MASK_DW_PER (GBLK * 512)           // 400384 mask dwords per gemm
#define MASK_BLKS (3 * MASK_DW_PER / 256)  // 4692 mask-gen blocks

typedef __attribute__((ext_vector_type(8))) short bf16x8;
typedef __attribute__((ext_vector_type(4))) float f32x4;

// ---------------------------------------------------------------------------
// bf16 <-> f32 (RNE, matches HW/XLA rounding)
// ---------------------------------------------------------------------------
__device__ inline ushort f2b(float f) {
  uint32_t u = __float_as_uint(f);
  return (ushort)((u + 0x7FFFu + ((u >> 16) & 1u)) >> 16);
}
__device__ inline float b2f(ushort h) { return __uint_as_float(((uint32_t)h) << 16); }

// ---------------------------------------------------------------------------
// Async global->LDS 16B copy: lane deposits 16 B at lds_base + lane*16.
// ---------------------------------------------------------------------------
typedef __attribute__((address_space(3))) uint32_t lds_u32_t;
typedef const __attribute__((address_space(1))) uint32_t glb_u32_t;
__device__ __forceinline__ void ld_lds16(const ushort* g, ushort* lds) {
  __builtin_amdgcn_global_load_lds((glb_u32_t*)g, (lds_u32_t*)lds, 16, 0, 0);
}

// ---------------------------------------------------------------------------
// Threefry-2x32 (exact JAX: 20 rounds, 5 key injections) — verified R2
// ---------------------------------------------------------------------------
__host__ __device__ constexpr uint64_t tf2x32(uint32_t k0, uint32_t k1,
                                              uint32_t x0, uint32_t x1) {
  uint32_t ks2 = k0 ^ k1 ^ 0x1BD11BDAu;
  x0 += k0; x1 += k1;
#define TF_ROT(x, r) (((x) << (r)) | ((x) >> (32 - (r))))
#define TF_RND(r) { x0 += x1; x1 = TF_ROT(x1, r) ^ x0; }
  TF_RND(13) TF_RND(15) TF_RND(26) TF_RND(6)
  x0 += k1;  x1 += ks2 + 1u;
  TF_RND(17) TF_RND(29) TF_RND(16) TF_RND(24)
  x0 += ks2; x1 += k0 + 2u;
  TF_RND(13) TF_RND(15) TF_RND(26) TF_RND(6)
  x0 += k0;  x1 += k1 + 3u;
  TF_RND(17) TF_RND(29) TF_RND(16) TF_RND(24)
  x0 += k1;  x1 += ks2 + 4u;
  TF_RND(13) TF_RND(15) TF_RND(26) TF_RND(6)
  x0 += ks2; x1 += k0 + 5u;
#undef TF_RND
#undef TF_ROT
  return (uint64_t(x0) << 32) | uint64_t(x1);
}

constexpr uint64_t FOLD[4] = {
  tf2x32(0u, 42u, 0u, 0u),
  tf2x32(0u, 42u, 0u, 1u),
  tf2x32(0u, 42u, 0u, 2u),
  tf2x32(0u, 42u, 0u, 3u),
};

// ---------------------------------------------------------------------------
// Heterogeneous kernel #1: f32->bf16 conversion (blocks [0,2*nbPer)) +
// dropout keep-mask generation (blocks [2*nbPer, +MASK_BLKS)).
// Mask slice g: 0 -> key FOLD[1] (L0 new_t), 1 -> FOLD[0] (L0 new_s),
//               2 -> FOLD[2] (L1 new_s).
// Bit layout mirrors the gemm epilogue: thread gt of gemm-block gblk holds
// dwords 2*gt(+1); bit s=i*16+e*4+j covers rowg=gblk*64+i*16+q*4+e,
// colg=wave*64+j*16+r.  Keep test: bits>>9 < 7549747 (==0.9f*2^23, exact).
// ---------------------------------------------------------------------------
__global__ __launch_bounds__(256) void cvt_masks(const float* __restrict__ a,
                                                 const float* __restrict__ b,
                                                 ushort* __restrict__ oa,
                                                 ushort* __restrict__ ob,
                                                 uint32_t* __restrict__ masks,
                                                 int n4, int nbPer) {
  int blk = blockIdx.x;
  if (blk < 2 * nbPer) {
    const float* in = blk < nbPer ? a : b;
    ushort* out = blk < nbPer ? oa : ob;
    int i = (blk % nbPer) * 256 + threadIdx.x;
    if (i >= n4) return;
    float4 v = ((const float4*)in)[i];
    ushort4 o;
    o.x = f2b(v.x); o.y = f2b(v.y); o.z = f2b(v.z); o.w = f2b(v.w);
    ((ushort4*)out)[i] = o;
    return;
  }
  int d = (blk - 2 * nbPer) * 256 + threadIdx.x;      // mask dword index
  int g = d / MASK_DW_PER;                            // 0..2
  int w = d - g * MASK_DW_PER;
  int gt = w >> 1, half = w & 1;
  int gblk = gt >> 8, gtid = gt & 255;
  int wave = gtid >> 6, lane = gtid & 63;
  int q = lane >> 4, r = lane & 15;
  uint64_t fk = (g == 0) ? FOLD[1] : (g == 1 ? FOLD[0] : FOLD[2]);
  uint32_t kk0 = (uint32_t)(fk >> 32), kk1 = (uint32_t)fk;
  int mbase = gblk * GBM;
  uint32_t mword = 0;
#pragma unroll
  for (int bb = 0; bb < 32; ++bb) {
    int s = half * 32 + bb;
    int si = s >> 4, se = (s >> 2) & 3, sj = s & 3;
    uint32_t rowg = (uint32_t)(mbase + si * 16 + q * 4 + se);
    uint32_t colg = (uint32_t)(wave * 64 + sj * 16 + r);
    uint64_t rr = tf2x32(kk0, kk1, 0u, rowg * 256u + colg);
    uint32_t bits = (uint32_t)(rr >> 32) ^ (uint32_t)rr;
    mword |= (((bits >> 9) < 7549747u) ? 1u : 0u) << bb;
  }
  masks[d] = mword;
}

struct W6 {
  const float* s[6];
  ushort* d[6];
};
// W fp32 [256 k][256 n] -> Wt bf16 [256 n][256 k]; 16 blocks per weight
__global__ __launch_bounds__(256) void wcvt_t6(W6 p) {
  __shared__ ushort tile[64][65];
  int w = blockIdx.x >> 4;
  const float* W = p.s[w];
  ushort* Wt = p.d[w];
  int t = threadIdx.x;
  int ktile = (blockIdx.x >> 2) & 3, ntile = blockIdx.x & 3;
#pragma unroll
  for (int rep = 0; rep < 16; ++rep) {
    int lin = rep * 256 + t;
    int kk = lin >> 6, nn = lin & 63;
    tile[nn][kk] = f2b(W[(size_t)(ktile * 64 + kk) * 256 + ntile * 64 + nn]);
  }
  __syncthreads();
#pragma unroll
  for (int rep = 0; rep < 16; ++rep) {
    int lin = rep * 256 + t;
    int nn = lin >> 6, kk = lin & 63;
    Wt[(size_t)(ntile * 64 + nn) * 256 + ktile * 64 + kk] = tile[nn][kk];
  }
}

// ---------------------------------------------------------------------------
// CSR build (two-level scan, verified R6)
// ---------------------------------------------------------------------------
__global__ __launch_bounds__(256) void csr_hist2(const int* __restrict__ ei_a,
                                                 const int* __restrict__ ei_b,
                                                 int* __restrict__ cur_a,
                                                 int* __restrict__ cur_b,
                                                 int nE, int nbPer) {
  int blk = blockIdx.x;
  const int* ei = blk < nbPer ? ei_a : ei_b;
  int* cur = blk < nbPer ? cur_a : cur_b;
  int e = (blk % nbPer) * 256 + threadIdx.x;
  if (e < nE) atomicAdd(cur + ei[nE + e], 1);
}

#define SB 1024
__global__ __launch_bounds__(SB) void scan_partial(const int* __restrict__ cur_a,
                                                   const int* __restrict__ cur_b,
                                                   int* __restrict__ bsum,
                                                   int n, int nbPer) {
  __shared__ int red[SB];
  int b = blockIdx.x;
  const int* cnt = b < nbPer ? cur_a : cur_b;
  int i = (b % nbPer) * SB + threadIdx.x;
  red[threadIdx.x] = (i < n) ? cnt[i] : 0;
  __syncthreads();
  for (int d = SB / 2; d > 0; d >>= 1) {
    if (threadIdx.x < d) red[threadIdx.x] += red[threadIdx.x + d];
    __syncthreads();
  }
  if (threadIdx.x == 0) bsum[b] = red[0];
}

__global__ __launch_bounds__(128) void scan_base(int* __restrict__ bsum, int nbPer) {
  __shared__ int buf[2][64];
  int half = threadIdx.x >> 6;
  int t = threadIdx.x & 63;
  buf[half][t] = (t < nbPer) ? bsum[half * nbPer + t] : 0;
  __syncthreads();
  for (int d = 1; d < 64; d <<= 1) {
    int v = (t >= d) ? buf[half][t - d] : 0;
    __syncthreads();
    buf[half][t] += v;
    __syncthreads();
  }
  if (t < nbPer) bsum[half * nbPer + t] = (t == 0) ? 0 : buf[half][t - 1];
}

__global__ __launch_bounds__(SB) void scan_final(int* __restrict__ cur_a,
                                                 int* __restrict__ cur_b,
                                                 int* __restrict__ offs_a,
                                                 int* __restrict__ offs_b,
                                                 const int* __restrict__ bsum,
                                                 int n, int nbPer) {
  __shared__ int part[SB];
  int b = blockIdx.x;
  bool first = b < nbPer;
  int* cur = first ? cur_a : cur_b;
  int* offs = first ? offs_a : offs_b;
  int i = (b % nbPer) * SB + threadIdx.x;
  int v = (i < n) ? cur[i] : 0;
  part[threadIdx.x] = v;
  __syncthreads();
  for (int d = 1; d < SB; d <<= 1) {
    int tv = (threadIdx.x >= d) ? part[threadIdx.x - d] : 0;
    __syncthreads();
    part[threadIdx.x] += tv;
    __syncthreads();
  }
  int excl = part[threadIdx.x] - v + bsum[b];
  if (i < n) {
    offs[i] = excl;
    cur[i] = 0;
  }
  if (i == n - 1) offs[n] = excl + v;
}

__global__ __launch_bounds__(256) void csr_fill2(const int* __restrict__ ei_a,
                                                 const int* __restrict__ ei_b,
                                                 const int* __restrict__ offs_a,
                                                 const int* __restrict__ offs_b,
                                                 int* __restrict__ cur_a,
                                                 int* __restrict__ cur_b,
                                                 int* __restrict__ adj_a,
                                                 int* __restrict__ adj_b,
                                                 int nE, int nbPer) {
  int blk = blockIdx.x;
  bool first = blk < nbPer;
  const int* ei = first ? ei_a : ei_b;
  const int* offs = first ? offs_a : offs_b;
  int* cur = first ? cur_a : cur_b;
  int* adj = first ? adj_a : adj_b;
  int e = (blk % nbPer) * 256 + threadIdx.x;
  if (e >= nE) return;
  int dst = ei[nE + e];
  int pos = atomicAdd(cur + dst, 1);
  adj[offs[dst] + pos] = ei[e];
}

// ---------------------------------------------------------------------------
// Segment-mean gather, bf16 in/out, fp32 accumulate. One wave per row.
// gather2: both L0 relations in one launch (independent in/out buffers).
// ---------------------------------------------------------------------------
__device__ __forceinline__ void gather_row(const ushort* __restrict__ x,
                                           const int* __restrict__ offs,
                                           const int* __restrict__ adj,
                                           ushort* __restrict__ m,
                                           int row, int lane) {
  int start = offs[row], end = offs[row + 1];
  float a0 = 0.f, a1 = 0.f, a2 = 0.f, a3 = 0.f;
  for (int e = start; e < end; ++e) {
    int s = adj[e];
    ushort4 v = *(const ushort4*)(x + (size_t)s * DIN + lane * 4);
    a0 += b2f(v.x); a1 += b2f(v.y); a2 += b2f(v.z); a3 += b2f(v.w);
  }
  float inv = 1.0f / fmaxf((float)(end - start), 1.0f);
  ushort4 o;
  o.x = f2b(a0 * inv); o.y = f2b(a1 * inv); o.z = f2b(a2 * inv); o.w = f2b(a3 * inv);
  *(ushort4*)(m + (size_t)row * DIN + lane * 4) = o;
}

__global__ __launch_bounds__(256) void gather_mean_h(const ushort* __restrict__ x,
                                                     const int* __restrict__ offs,
                                                     const int* __restrict__ adj,
                                                     ushort* __restrict__ m,
                                                     int nRows) {
  int row = blockIdx.x * 4 + (threadIdx.x >> 6);
  if (row >= nRows) return;
  gather_row(x, offs, adj, m, row, threadIdx.x & 63);
}

__global__ __launch_bounds__(256) void gather2_mean_h(
    const ushort* __restrict__ xa, const int* __restrict__ offsa,
    const int* __restrict__ adja, ushort* __restrict__ ma,
    const ushort* __restrict__ xb, const int* __restrict__ offsb,
    const int* __restrict__ adjb, ushort* __restrict__ mb,
    int nRows, int nbPer) {
  int blk = blockIdx.x;
  bool first = blk < nbPer;
  int row = (blk % nbPer) * 4 + (threadIdx.x >> 6);
  if (row >= nRows) return;
  if (first) gather_row(xa, offsa, adja, ma, row, threadIdx.x & 63);
  else       gather_row(xb, offsb, adjb, mb, row, threadIdx.x & 63);
}

// ---------------------------------------------------------------------------
// MFMA dual GEMM v3: C = dropout(leaky(A1@W1 + A2@W2 + bias))  [bf16 in/out]
// R7 post-mortem: in-kernel threefry blew VGPR to 132 (occupancy cliff at
// 128). v3: masks precomputed (cvt_masks); uint2 mask loaded before K-loop.
// __launch_bounds__(256,4) pins <=128 VGPR -> 4 waves/SIMD; LDS 40KB -> 4
// blocks/CU. Async global_load_lds staging (verified R7).
// ---------------------------------------------------------------------------
__global__ __launch_bounds__(256, 4) void gemm_dual_mfma(
    const ushort* __restrict__ A1, const ushort* __restrict__ A2,
    const ushort* __restrict__ W1t, const ushort* __restrict__ W2t,
    const float* __restrict__ bias, const uint2* __restrict__ mk,
    ushort* __restrict__ C, int M) {
  __shared__ ushort sA[2][GBM * 32];    // 4 KB per buffer
  __shared__ ushort sB[2][HID * 32];    // 16 KB per buffer
  const int tid = threadIdx.x;
  const int wave = tid >> 6, lane = tid & 63;
  const int q = lane >> 4, r = lane & 15;
  const int mbase = blockIdx.x * GBM;

  const uint2 km = mk[blockIdx.x * 256 + tid];  // issued early, hidden by K-loop

  f32x4 acc[4][4] = {};

  const int arow = tid >> 2;        // 0..63
  const int akc = (tid & 3) * 8;    // short offset 0,8,16,24
  const int agrow = min(mbase + arow, M - 1);
  const ushort* a1p = A1 + (size_t)agrow * DIN + akc;
  const ushort* a2p = A2 + (size_t)agrow * DIN + akc;
  const ushort* w1b = W1t + (size_t)arow * DIN + akc;
  const ushort* w2b = W2t + (size_t)arow * DIN + akc;
  ushort* ldsA0 = &sA[0][wave * 512];
  ushort* ldsA1 = &sA[1][wave * 512];

#pragma unroll
  for (int t = 0; t < 8; ++t) {
    const int kt = t * 32;
    __syncthreads();  // prior iter's LDS reads done before DMA overwrites
    ld_lds16(a1p + kt, ldsA0);
    ld_lds16(a2p + kt, ldsA1);
#pragma unroll
    for (int c = 0; c < 4; ++c) {
      ld_lds16(w1b + c * (64 * DIN) + kt, &sB[0][c * 2048 + wave * 512]);
      ld_lds16(w2b + c * (64 * DIN) + kt, &sB[1][c * 2048 + wave * 512]);
    }
    __syncthreads();  // drains vmcnt(0): DMA complete
#pragma unroll
    for (int ph = 0; ph < 2; ++ph) {
      bf16x8 af[4], bfr[4];
#pragma unroll
      for (int i = 0; i < 4; ++i)
        af[i] = *(const bf16x8*)&sA[ph][(i * 16 + r) * 32 + q * 8];
#pragma unroll
      for (int j = 0; j < 4; ++j)
        bfr[j] = *(const bf16x8*)&sB[ph][(wave * 64 + j * 16 + r) * 32 + q * 8];
#pragma unroll
      for (int i = 0; i < 4; ++i)
#pragma unroll
        for (int j = 0; j < 4; ++j)
          acc[i][j] = __builtin_amdgcn_mfma_f32_16x16x32_bf16(af[i], bfr[j],
                                                              acc[i][j], 0, 0, 0);
    }
  }

  // Epilogue: bias + leaky + masked dropout scale + bf16 store
  float bj[4];
#pragma unroll
  for (int j = 0; j < 4; ++j) bj[j] = bias[wave * 64 + j * 16 + r];
#pragma unroll
  for (int i = 0; i < 4; ++i) {
#pragma unroll
    for (int e = 0; e < 4; ++e) {
      int rowg = mbase + i * 16 + q * 4 + e;
      if (rowg >= M) continue;
#pragma unroll
      for (int j = 0; j < 4; ++j) {
        const int s = i * 16 + e * 4 + j;
        int colg = wave * 64 + j * 16 + r;
        float v = acc[i][j][e] + bj[j];
        v = v >= 0.0f ? v : 0.01f * v;
        uint32_t keep = ((s < 32 ? km.x >> s : km.y >> (s - 32)) & 1u);
        v = keep ? v * (1.0f / 0.9f) : 0.0f;
        C[(size_t)rowg * HID + colg] = f2b(v);
      }
    }
  }
}

// ---------------------------------------------------------------------------
// Final projection: [M,256] bf16 @ [256,16] fp32 + bout -> fp32
// ---------------------------------------------------------------------------
__global__ __launch_bounds__(256) void out_gemm_h(const ushort* __restrict__ X,
                                                  const float* __restrict__ Wout,
                                                  const float* __restrict__ bout,
                                                  float* __restrict__ C, int M) {
  __shared__ float sW[DIN * DOUT];
  int tid = threadIdx.x;
#pragma unroll
  for (int i = 0; i < (DIN * DOUT) / 256; ++i) sW[i * 256 + tid] = Wout[i * 256 + tid];
  __syncthreads();
  int rr = tid >> 4, c = tid & 15;
  int row = blockIdx.x * 16 + rr;
  if (row >= M) return;
  float acc = bout[c];
  const ushort* xp = X + (size_t)row * DIN;
  for (int k = 0; k < DIN; k += 8) {
    uint4 u = *(const uint4*)(xp + k);
    const ushort* us = (const ushort*)&u;
#pragma unroll
    for (int t = 0; t < 8; ++t) acc += b2f(us[t]) * sW[(k + t) * DOUT + c];
  }
  C[(size_t)row * DOUT + c] = acc;
}

// ---------------------------------------------------------------------------
// Workspace (~138 MB < 154 MB proven safe)
// ---------------------------------------------------------------------------
extern "C" void kernel_launch(void* const* d_in, const int* in_sizes, int n_in,
                              void* d_out, int out_size, void* d_ws, size_t ws_size,
                              hipStream_t stream) {
  const float* x_source = (const float*)d_in[0];
  const float* x_target = (const float*)d_in[1];
  const int* ei_st = (const int*)d_in[2];
  const int* ei_ts = (const int*)d_in[3];
  const float* Wl_st = (const float*)d_in[4];
  const float* Wr_st = (const float*)d_in[5];
  const float* b_st  = (const float*)d_in[6];
  const float* Wl_ts = (const float*)d_in[7];
  const float* Wr_ts = (const float*)d_in[8];
  const float* b_ts  = (const float*)d_in[9];
  const float* Wout  = (const float*)d_in[10];
  const float* bout  = (const float*)d_in[11];
  float* out = (float*)d_out;

  const size_t F = (size_t)NSRC * DIN;  // 12.8M elements
  const size_t WM = (size_t)DIN * HID;  // 65536
  const int nbScan = (NSRC + SB - 1) / SB;  // 49 (NSRC==NTGT)
  const size_t intCount = (NTGT + 1) + (NSRC + 1) + 2 * NE + NTGT + NSRC +
                          2 * nbScan + 3 * MASK_DW_PER;
  const size_t need = (5 * F + 6 * WM) * sizeof(ushort) + intCount * sizeof(int);
  if (ws_size < need) return;

  ushort* xs0h = (ushort*)d_ws;
  ushort* xt0h = xs0h + F;
  ushort* B0h  = xt0h + F;
  ushort* B1h  = B0h + F;
  ushort* B2h  = B1h + F;
  ushort* wt0  = B2h + F;       // Wl_st[0]^T
  ushort* wt1  = wt0 + WM;      // Wr_st[0]^T
  ushort* wt2  = wt1 + WM;      // Wl_ts[0]^T
  ushort* wt3  = wt2 + WM;      // Wr_ts[0]^T
  ushort* wt4  = wt3 + WM;      // Wl_ts[1]^T
  ushort* wt5  = wt4 + WM;      // Wr_ts[1]^T
  int* ip      = (int*)(wt5 + WM);
  int* offs_st = ip;
  int* offs_ts = offs_st + NTGT + 1;
  int* adj_st  = offs_ts + NSRC + 1;
  int* adj_ts  = adj_st + NE;
  int* cur_t   = adj_ts + NE;        // [NTGT] + [NSRC] adjacent for one memset
  int* cur_s   = cur_t + NTGT;
  int* bsum    = cur_s + NSRC;       // [2*nbScan]
  uint32_t* masks = (uint32_t*)(bsum + 2 * nbScan);  // [3*MASK_DW_PER]

  const int EB = (NE + 255) / 256;
  const int CB = (int)(F / 4 + 255) / 256;  // cvt blocks per input (12500)
  const int GGB = (int)((NTGT / 4));        // gather blocks per relation (12500)

  // ---- Convert inputs to bf16 + generate all 3 dropout masks ----
  cvt_masks<<<2 * CB + MASK_BLKS, 256, 0, stream>>>(
      x_source, x_target, xs0h, xt0h, masks, (int)(F / 4), CB);
  W6 wb;
  wb.s[0] = Wl_st;      wb.d[0] = wt0;
  wb.s[1] = Wr_st;      wb.d[1] = wt1;
  wb.s[2] = Wl_ts;      wb.d[2] = wt2;
  wb.s[3] = Wr_ts;      wb.d[3] = wt3;
  wb.s[4] = Wl_ts + WM; wb.d[4] = wt4;
  wb.s[5] = Wr_ts + WM; wb.d[5] = wt5;
  wcvt_t6<<<96, 256, 0, stream>>>(wb);

  // ---- Build both CSRs concurrently ----
  hipMemsetAsync(cur_t, 0, (NTGT + NSRC) * sizeof(int), stream);
  csr_hist2<<<2 * EB, 256, 0, stream>>>(ei_st, ei_ts, cur_t, cur_s, NE, EB);
  scan_partial<<<2 * nbScan, SB, 0, stream>>>(cur_t, cur_s, bsum, NTGT, nbScan);
  scan_base<<<1, 128, 0, stream>>>(bsum, nbScan);
  scan_final<<<2 * nbScan, SB, 0, stream>>>(cur_t, cur_s, offs_st, offs_ts,
                                            bsum, NTGT, nbScan);
  csr_fill2<<<2 * EB, 256, 0, stream>>>(ei_st, ei_ts, offs_st, offs_ts,
                                        cur_t, cur_s, adj_st, adj_ts, NE, EB);

  // ---------------- Layer 0 ----------------
  gather2_mean_h<<<2 * GGB, 256, 0, stream>>>(xs0h, offs_st, adj_st, B0h,
                                              xt0h, offs_ts, adj_ts, B1h,
                                              NTGT, GGB);

  // new_t -> B2h (mask slice 0 = FOLD[1]);  new_s -> B0h (slice 1 = FOLD[0])
  gemm_dual_mfma<<<GBLK, 256, 0, stream>>>(
      B0h, xt0h, wt0, wt1, b_st, (const uint2*)(masks), B2h, NTGT);
  gemm_dual_mfma<<<GBLK, 256, 0, stream>>>(
      B1h, xs0h, wt2, wt3, b_ts, (const uint2*)(masks + MASK_DW_PER), B0h, NSRC);

  // ---------------- Layer 1 (source side only; target side dead) ----------
  gather_mean_h<<<GGB, 256, 0, stream>>>(B2h, offs_ts, adj_ts, B1h, NSRC);
  gemm_dual_mfma<<<GBLK, 256, 0, stream>>>(
      B1h, B0h, wt4, wt5, b_ts + HID, (const uint2*)(masks + 2 * MASK_DW_PER),
      B2h, NSRC);

  out_gemm_h<<<(NSRC + 15) / 16, 256, 0, stream>>>(B2h, Wout, bout, out, NSRC);
}

// Round 9
// 510.614 us; speedup vs baseline: 8.0277x; 1.0113x over previous
//
#include <hip/hip_runtime.h>
#include <stdint.h>

// Problem constants (fixed by reference)
#define NSRC 50000
#define NTGT 50000
#define NE   320000
#define DIN  256
#define HID  256
#define DOUT 16

#define GBM 64
#define GBLK ((NSRC + GBM - 1) / GBM)      // 782 gemm blocks
#define MASK_DW_PER (GBLK * 512)           // 400384 mask dwords per gemm
#define MASK_BLKS (3 * MASK_DW_PER / 256)  // 4692 mask-gen blocks

typedef __attribute__((ext_vector_type(8))) short bf16x8;
typedef __attribute__((ext_vector_type(4))) float f32x4;

// ---------------------------------------------------------------------------
// bf16 <-> f32 (RNE, matches HW/XLA rounding)
// ---------------------------------------------------------------------------
__device__ inline ushort f2b(float f) {
  uint32_t u = __float_as_uint(f);
  return (ushort)((u + 0x7FFFu + ((u >> 16) & 1u)) >> 16);
}
__device__ inline float b2f(ushort h) { return __uint_as_float(((uint32_t)h) << 16); }

// ---------------------------------------------------------------------------
// Async global->LDS 16B copy: lane deposits 16 B at lds_base + lane*16.
// ---------------------------------------------------------------------------
typedef __attribute__((address_space(3))) uint32_t lds_u32_t;
typedef const __attribute__((address_space(1))) uint32_t glb_u32_t;
__device__ __forceinline__ void ld_lds16(const ushort* g, ushort* lds) {
  __builtin_amdgcn_global_load_lds((glb_u32_t*)g, (lds_u32_t*)lds, 16, 0, 0);
}

// ---------------------------------------------------------------------------
// Threefry-2x32 (exact JAX: 20 rounds, 5 key injections) — verified R2
// ---------------------------------------------------------------------------
__host__ __device__ constexpr uint64_t tf2x32(uint32_t k0, uint32_t k1,
                                              uint32_t x0, uint32_t x1) {
  uint32_t ks2 = k0 ^ k1 ^ 0x1BD11BDAu;
  x0 += k0; x1 += k1;
#define TF_ROT(x, r) (((x) << (r)) | ((x) >> (32 - (r))))
#define TF_RND(r) { x0 += x1; x1 = TF_ROT(x1, r) ^ x0; }
  TF_RND(13) TF_RND(15) TF_RND(26) TF_RND(6)
  x0 += k1;  x1 += ks2 + 1u;
  TF_RND(17) TF_RND(29) TF_RND(16) TF_RND(24)
  x0 += ks2; x1 += k0 + 2u;
  TF_RND(13) TF_RND(15) TF_RND(26) TF_RND(6)
  x0 += k0;  x1 += k1 + 3u;
  TF_RND(17) TF_RND(29) TF_RND(16) TF_RND(24)
  x0 += k1;  x1 += ks2 + 4u;
  TF_RND(13) TF_RND(15) TF_RND(26) TF_RND(6)
  x0 += ks2; x1 += k0 + 5u;
#undef TF_RND
#undef TF_ROT
  return (uint64_t(x0) << 32) | uint64_t(x1);
}

constexpr uint64_t FOLD[4] = {
  tf2x32(0u, 42u, 0u, 0u),
  tf2x32(0u, 42u, 0u, 1u),
  tf2x32(0u, 42u, 0u, 2u),
  tf2x32(0u, 42u, 0u, 3u),
};

// ---------------------------------------------------------------------------
// Pure f32->bf16 conversion (both inputs, one launch). Memory-bound.
// ---------------------------------------------------------------------------
__global__ __launch_bounds__(256) void cvt2_f32_bf16(const float* __restrict__ a,
                                                     const float* __restrict__ b,
                                                     ushort* __restrict__ oa,
                                                     ushort* __restrict__ ob,
                                                     int n4, int nbPer) {
  int blk = blockIdx.x;
  const float* in = blk < nbPer ? a : b;
  ushort* out = blk < nbPer ? oa : ob;
  int i = (blk % nbPer) * 256 + threadIdx.x;
  if (i >= n4) return;
  float4 v = ((const float4*)in)[i];
  ushort4 o;
  o.x = f2b(v.x); o.y = f2b(v.y); o.z = f2b(v.z); o.w = f2b(v.w);
  ((ushort4*)out)[i] = o;
}

// ---------------------------------------------------------------------------
// Dropout keep-mask word for mask-dword index d (bit layout mirrors the gemm
// epilogue; verified bit-identical R8). Keep test: bits>>9 < 7549747
// (== 0.9f * 2^23, exact).
// ---------------------------------------------------------------------------
__device__ __forceinline__ void mask_word(uint32_t* __restrict__ masks, int d) {
  int g = d / MASK_DW_PER;                            // 0..2
  int w = d - g * MASK_DW_PER;
  int gt = w >> 1, half = w & 1;
  int gblk = gt >> 8, gtid = gt & 255;
  int wave = gtid >> 6, lane = gtid & 63;
  int q = lane >> 4, r = lane & 15;
  uint64_t fk = (g == 0) ? FOLD[1] : (g == 1 ? FOLD[0] : FOLD[2]);
  uint32_t kk0 = (uint32_t)(fk >> 32), kk1 = (uint32_t)fk;
  int mbase = gblk * GBM;
  uint32_t mword = 0;
#pragma unroll
  for (int bb = 0; bb < 32; ++bb) {
    int s = half * 32 + bb;
    int si = s >> 4, se = (s >> 2) & 3, sj = s & 3;
    uint32_t rowg = (uint32_t)(mbase + si * 16 + q * 4 + se);
    uint32_t colg = (uint32_t)(wave * 64 + sj * 16 + r);
    uint64_t rr = tf2x32(kk0, kk1, 0u, rowg * 256u + colg);
    uint32_t bits = (uint32_t)(rr >> 32) ^ (uint32_t)rr;
    mword |= (((bits >> 9) < 7549747u) ? 1u : 0u) << bb;
  }
  masks[d] = mword;
}

struct W6 {
  const float* s[6];
  ushort* d[6];
};
// W fp32 [256 k][256 n] -> Wt bf16 [256 n][256 k]; 16 blocks per weight
__global__ __launch_bounds__(256) void wcvt_t6(W6 p) {
  __shared__ ushort tile[64][65];
  int w = blockIdx.x >> 4;
  const float* W = p.s[w];
  ushort* Wt = p.d[w];
  int t = threadIdx.x;
  int ktile = (blockIdx.x >> 2) & 3, ntile = blockIdx.x & 3;
#pragma unroll
  for (int rep = 0; rep < 16; ++rep) {
    int lin = rep * 256 + t;
    int kk = lin >> 6, nn = lin & 63;
    tile[nn][kk] = f2b(W[(size_t)(ktile * 64 + kk) * 256 + ntile * 64 + nn]);
  }
  __syncthreads();
#pragma unroll
  for (int rep = 0; rep < 16; ++rep) {
    int lin = rep * 256 + t;
    int nn = lin >> 6, kk = lin & 63;
    Wt[(size_t)(ntile * 64 + nn) * 256 + ktile * 64 + kk] = tile[nn][kk];
  }
}

// ---------------------------------------------------------------------------
// CSR build (two-level scan, verified R6)
// ---------------------------------------------------------------------------
__global__ __launch_bounds__(256) void csr_hist2(const int* __restrict__ ei_a,
                                                 const int* __restrict__ ei_b,
                                                 int* __restrict__ cur_a,
                                                 int* __restrict__ cur_b,
                                                 int nE, int nbPer) {
  int blk = blockIdx.x;
  const int* ei = blk < nbPer ? ei_a : ei_b;
  int* cur = blk < nbPer ? cur_a : cur_b;
  int e = (blk % nbPer) * 256 + threadIdx.x;
  if (e < nE) atomicAdd(cur + ei[nE + e], 1);
}

#define SB 1024
__global__ __launch_bounds__(SB) void scan_partial(const int* __restrict__ cur_a,
                                                   const int* __restrict__ cur_b,
                                                   int* __restrict__ bsum,
                                                   int n, int nbPer) {
  __shared__ int red[SB];
  int b = blockIdx.x;
  const int* cnt = b < nbPer ? cur_a : cur_b;
  int i = (b % nbPer) * SB + threadIdx.x;
  red[threadIdx.x] = (i < n) ? cnt[i] : 0;
  __syncthreads();
  for (int d = SB / 2; d > 0; d >>= 1) {
    if (threadIdx.x < d) red[threadIdx.x] += red[threadIdx.x + d];
    __syncthreads();
  }
  if (threadIdx.x == 0) bsum[b] = red[0];
}

__global__ __launch_bounds__(128) void scan_base(int* __restrict__ bsum, int nbPer) {
  __shared__ int buf[2][64];
  int half = threadIdx.x >> 6;
  int t = threadIdx.x & 63;
  buf[half][t] = (t < nbPer) ? bsum[half * nbPer + t] : 0;
  __syncthreads();
  for (int d = 1; d < 64; d <<= 1) {
    int v = (t >= d) ? buf[half][t - d] : 0;
    __syncthreads();
    buf[half][t] += v;
    __syncthreads();
  }
  if (t < nbPer) bsum[half * nbPer + t] = (t == 0) ? 0 : buf[half][t - 1];
}

__global__ __launch_bounds__(SB) void scan_final(int* __restrict__ cur_a,
                                                 int* __restrict__ cur_b,
                                                 int* __restrict__ offs_a,
                                                 int* __restrict__ offs_b,
                                                 const int* __restrict__ bsum,
                                                 int n, int nbPer) {
  __shared__ int part[SB];
  int b = blockIdx.x;
  bool first = b < nbPer;
  int* cur = first ? cur_a : cur_b;
  int* offs = first ? offs_a : offs_b;
  int i = (b % nbPer) * SB + threadIdx.x;
  int v = (i < n) ? cur[i] : 0;
  part[threadIdx.x] = v;
  __syncthreads();
  for (int d = 1; d < SB; d <<= 1) {
    int tv = (threadIdx.x >= d) ? part[threadIdx.x - d] : 0;
    __syncthreads();
    part[threadIdx.x] += tv;
    __syncthreads();
  }
  int excl = part[threadIdx.x] - v + bsum[b];
  if (i < n) {
    offs[i] = excl;
    cur[i] = 0;
  }
  if (i == n - 1) offs[n] = excl + v;
}

__global__ __launch_bounds__(256) void csr_fill2(const int* __restrict__ ei_a,
                                                 const int* __restrict__ ei_b,
                                                 const int* __restrict__ offs_a,
                                                 const int* __restrict__ offs_b,
                                                 int* __restrict__ cur_a,
                                                 int* __restrict__ cur_b,
                                                 int* __restrict__ adj_a,
                                                 int* __restrict__ adj_b,
                                                 int nE, int nbPer) {
  int blk = blockIdx.x;
  bool first = blk < nbPer;
  const int* ei = first ? ei_a : ei_b;
  const int* offs = first ? offs_a : offs_b;
  int* cur = first ? cur_a : cur_b;
  int* adj = first ? adj_a : adj_b;
  int e = (blk % nbPer) * 256 + threadIdx.x;
  if (e >= nE) return;
  int dst = ei[nE + e];
  int pos = atomicAdd(cur + dst, 1);
  adj[offs[dst] + pos] = ei[e];
}

// ---------------------------------------------------------------------------
// Segment-mean gather, bf16 in/out, fp32 accumulate. One wave per row.
// gather2m: both L0 relations + ALL dropout-mask generation in one launch.
// R8 post-mortem: mask hashing (38.4M threefry, ~60-70us chip VALU) ran in a
// dedicated-grid half that serialized with its own conversion blocks. Gathers
// are memory-latency-bound with ~1% VALUBusy (R2 scatter evidence) -> mask
// VALU co-schedules with gather stalls (m114: time = max, not sum).
// ---------------------------------------------------------------------------
__device__ __forceinline__ void gather_row(const ushort* __restrict__ x,
                                           const int* __restrict__ offs,
                                           const int* __restrict__ adj,
                                           ushort* __restrict__ m,
                                           int row, int lane) {
  int start = offs[row], end = offs[row + 1];
  float a0 = 0.f, a1 = 0.f, a2 = 0.f, a3 = 0.f;
  for (int e = start; e < end; ++e) {
    int s = adj[e];
    ushort4 v = *(const ushort4*)(x + (size_t)s * DIN + lane * 4);
    a0 += b2f(v.x); a1 += b2f(v.y); a2 += b2f(v.z); a3 += b2f(v.w);
  }
  float inv = 1.0f / fmaxf((float)(end - start), 1.0f);
  ushort4 o;
  o.x = f2b(a0 * inv); o.y = f2b(a1 * inv); o.z = f2b(a2 * inv); o.w = f2b(a3 * inv);
  *(ushort4*)(m + (size_t)row * DIN + lane * 4) = o;
}

__global__ __launch_bounds__(256) void gather_mean_h(const ushort* __restrict__ x,
                                                     const int* __restrict__ offs,
                                                     const int* __restrict__ adj,
                                                     ushort* __restrict__ m,
                                                     int nRows) {
  int row = blockIdx.x * 4 + (threadIdx.x >> 6);
  if (row >= nRows) return;
  gather_row(x, offs, adj, m, row, threadIdx.x & 63);
}

__global__ __launch_bounds__(256) void gather2m_mean_h(
    const ushort* __restrict__ xa, const int* __restrict__ offsa,
    const int* __restrict__ adja, ushort* __restrict__ ma,
    const ushort* __restrict__ xb, const int* __restrict__ offsb,
    const int* __restrict__ adjb, ushort* __restrict__ mb,
    uint32_t* __restrict__ masks, int nRows, int nbPer) {
  int blk = blockIdx.x;
  if (blk >= 2 * nbPer) {  // dropout-mask generation blocks
    mask_word(masks, (blk - 2 * nbPer) * 256 + threadIdx.x);
    return;
  }
  bool first = blk < nbPer;
  int row = (blk % nbPer) * 4 + (threadIdx.x >> 6);
  if (row >= nRows) return;
  if (first) gather_row(xa, offsa, adja, ma, row, threadIdx.x & 63);
  else       gather_row(xb, offsb, adjb, mb, row, threadIdx.x & 63);
}

// ---------------------------------------------------------------------------
// MFMA dual GEMM v3 (verified R8): C = dropout(leaky(A1@W1 + A2@W2 + bias)).
// Masks precomputed; async global_load_lds staging; 40KB LDS; bounds (256,4).
// ---------------------------------------------------------------------------
__global__ __launch_bounds__(256, 4) void gemm_dual_mfma(
    const ushort* __restrict__ A1, const ushort* __restrict__ A2,
    const ushort* __restrict__ W1t, const ushort* __restrict__ W2t,
    const float* __restrict__ bias, const uint2* __restrict__ mk,
    ushort* __restrict__ C, int M) {
  __shared__ ushort sA[2][GBM * 32];    // 4 KB per buffer
  __shared__ ushort sB[2][HID * 32];    // 16 KB per buffer
  const int tid = threadIdx.x;
  const int wave = tid >> 6, lane = tid & 63;
  const int q = lane >> 4, r = lane & 15;
  const int mbase = blockIdx.x * GBM;

  const uint2 km = mk[blockIdx.x * 256 + tid];  // issued early, hidden by K-loop

  f32x4 acc[4][4] = {};

  const int arow = tid >> 2;        // 0..63
  const int akc = (tid & 3) * 8;    // short offset 0,8,16,24
  const int agrow = min(mbase + arow, M - 1);
  const ushort* a1p = A1 + (size_t)agrow * DIN + akc;
  const ushort* a2p = A2 + (size_t)agrow * DIN + akc;
  const ushort* w1b = W1t + (size_t)arow * DIN + akc;
  const ushort* w2b = W2t + (size_t)arow * DIN + akc;
  ushort* ldsA0 = &sA[0][wave * 512];
  ushort* ldsA1 = &sA[1][wave * 512];

#pragma unroll
  for (int t = 0; t < 8; ++t) {
    const int kt = t * 32;
    __syncthreads();  // prior iter's LDS reads done before DMA overwrites
    ld_lds16(a1p + kt, ldsA0);
    ld_lds16(a2p + kt, ldsA1);
#pragma unroll
    for (int c = 0; c < 4; ++c) {
      ld_lds16(w1b + c * (64 * DIN) + kt, &sB[0][c * 2048 + wave * 512]);
      ld_lds16(w2b + c * (64 * DIN) + kt, &sB[1][c * 2048 + wave * 512]);
    }
    __syncthreads();  // drains vmcnt(0): DMA complete
#pragma unroll
    for (int ph = 0; ph < 2; ++ph) {
      bf16x8 af[4], bfr[4];
#pragma unroll
      for (int i = 0; i < 4; ++i)
        af[i] = *(const bf16x8*)&sA[ph][(i * 16 + r) * 32 + q * 8];
#pragma unroll
      for (int j = 0; j < 4; ++j)
        bfr[j] = *(const bf16x8*)&sB[ph][(wave * 64 + j * 16 + r) * 32 + q * 8];
#pragma unroll
      for (int i = 0; i < 4; ++i)
#pragma unroll
        for (int j = 0; j < 4; ++j)
          acc[i][j] = __builtin_amdgcn_mfma_f32_16x16x32_bf16(af[i], bfr[j],
                                                              acc[i][j], 0, 0, 0);
    }
  }

  // Epilogue: bias + leaky + masked dropout scale + bf16 store
  float bj[4];
#pragma unroll
  for (int j = 0; j < 4; ++j) bj[j] = bias[wave * 64 + j * 16 + r];
#pragma unroll
  for (int i = 0; i < 4; ++i) {
#pragma unroll
    for (int e = 0; e < 4; ++e) {
      int rowg = mbase + i * 16 + q * 4 + e;
      if (rowg >= M) continue;
#pragma unroll
      for (int j = 0; j < 4; ++j) {
        const int s = i * 16 + e * 4 + j;
        int colg = wave * 64 + j * 16 + r;
        float v = acc[i][j][e] + bj[j];
        v = v >= 0.0f ? v : 0.01f * v;
        uint32_t keep = ((s < 32 ? km.x >> s : km.y >> (s - 32)) & 1u);
        v = keep ? v * (1.0f / 0.9f) : 0.0f;
        C[(size_t)rowg * HID + colg] = f2b(v);
      }
    }
  }
}

// ---------------------------------------------------------------------------
// Final projection: [M,256] bf16 @ [256,16] fp32 + bout -> fp32
// ---------------------------------------------------------------------------
__global__ __launch_bounds__(256) void out_gemm_h(const ushort* __restrict__ X,
                                                  const float* __restrict__ Wout,
                                                  const float* __restrict__ bout,
                                                  float* __restrict__ C, int M) {
  __shared__ float sW[DIN * DOUT];
  int tid = threadIdx.x;
#pragma unroll
  for (int i = 0; i < (DIN * DOUT) / 256; ++i) sW[i * 256 + tid] = Wout[i * 256 + tid];
  __syncthreads();
  int rr = tid >> 4, c = tid & 15;
  int row = blockIdx.x * 16 + rr;
  if (row >= M) return;
  float acc = bout[c];
  const ushort* xp = X + (size_t)row * DIN;
  for (int k = 0; k < DIN; k += 8) {
    uint4 u = *(const uint4*)(xp + k);
    const ushort* us = (const ushort*)&u;
#pragma unroll
    for (int t = 0; t < 8; ++t) acc += b2f(us[t]) * sW[(k + t) * DOUT + c];
  }
  C[(size_t)row * DOUT + c] = acc;
}

// ---------------------------------------------------------------------------
// Workspace (~138 MB < 154 MB proven safe)
// ---------------------------------------------------------------------------
extern "C" void kernel_launch(void* const* d_in, const int* in_sizes, int n_in,
                              void* d_out, int out_size, void* d_ws, size_t ws_size,
                              hipStream_t stream) {
  const float* x_source = (const float*)d_in[0];
  const float* x_target = (const float*)d_in[1];
  const int* ei_st = (const int*)d_in[2];
  const int* ei_ts = (const int*)d_in[3];
  const float* Wl_st = (const float*)d_in[4];
  const float* Wr_st = (const float*)d_in[5];
  const float* b_st  = (const float*)d_in[6];
  const float* Wl_ts = (const float*)d_in[7];
  const float* Wr_ts = (const float*)d_in[8];
  const float* b_ts  = (const float*)d_in[9];
  const float* Wout  = (const float*)d_in[10];
  const float* bout  = (const float*)d_in[11];
  float* out = (float*)d_out;

  const size_t F = (size_t)NSRC * DIN;  // 12.8M elements
  const size_t WM = (size_t)DIN * HID;  // 65536
  const int nbScan = (NSRC + SB - 1) / SB;  // 49 (NSRC==NTGT)
  const size_t intCount = (NTGT + 1) + (NSRC + 1) + 2 * NE + NTGT + NSRC +
                          2 * nbScan + 3 * MASK_DW_PER;
  const size_t need = (5 * F + 6 * WM) * sizeof(ushort) + intCount * sizeof(int);
  if (ws_size < need) return;

  ushort* xs0h = (ushort*)d_ws;
  ushort* xt0h = xs0h + F;
  ushort* B0h  = xt0h + F;
  ushort* B1h  = B0h + F;
  ushort* B2h  = B1h + F;
  ushort* wt0  = B2h + F;       // Wl_st[0]^T
  ushort* wt1  = wt0 + WM;      // Wr_st[0]^T
  ushort* wt2  = wt1 + WM;      // Wl_ts[0]^T
  ushort* wt3  = wt2 + WM;      // Wr_ts[0]^T
  ushort* wt4  = wt3 + WM;      // Wl_ts[1]^T
  ushort* wt5  = wt4 + WM;      // Wr_ts[1]^T
  int* ip      = (int*)(wt5 + WM);
  int* offs_st = ip;
  int* offs_ts = offs_st + NTGT + 1;
  int* adj_st  = offs_ts + NSRC + 1;
  int* adj_ts  = adj_st + NE;
  int* cur_t   = adj_ts + NE;        // [NTGT] + [NSRC] adjacent for one memset
  int* cur_s   = cur_t + NTGT;
  int* bsum    = cur_s + NSRC;       // [2*nbScan]
  uint32_t* masks = (uint32_t*)(bsum + 2 * nbScan);  // [3*MASK_DW_PER]

  const int EB = (NE + 255) / 256;
  const int CB = (int)(F / 4 + 255) / 256;  // cvt blocks per input (12500)
  const int GGB = (int)((NTGT / 4));        // gather blocks per relation (12500)

  // ---- Convert inputs to bf16 ----
  cvt2_f32_bf16<<<2 * CB, 256, 0, stream>>>(x_source, x_target, xs0h, xt0h,
                                            (int)(F / 4), CB);
  W6 wb;
  wb.s[0] = Wl_st;      wb.d[0] = wt0;
  wb.s[1] = Wr_st;      wb.d[1] = wt1;
  wb.s[2] = Wl_ts;      wb.d[2] = wt2;
  wb.s[3] = Wr_ts;      wb.d[3] = wt3;
  wb.s[4] = Wl_ts + WM; wb.d[4] = wt4;
  wb.s[5] = Wr_ts + WM; wb.d[5] = wt5;
  wcvt_t6<<<96, 256, 0, stream>>>(wb);

  // ---- Build both CSRs concurrently ----
  hipMemsetAsync(cur_t, 0, (NTGT + NSRC) * sizeof(int), stream);
  csr_hist2<<<2 * EB, 256, 0, stream>>>(ei_st, ei_ts, cur_t, cur_s, NE, EB);
  scan_partial<<<2 * nbScan, SB, 0, stream>>>(cur_t, cur_s, bsum, NTGT, nbScan);
  scan_base<<<1, 128, 0, stream>>>(bsum, nbScan);
  scan_final<<<2 * nbScan, SB, 0, stream>>>(cur_t, cur_s, offs_st, offs_ts,
                                            bsum, NTGT, nbScan);
  csr_fill2<<<2 * EB, 256, 0, stream>>>(ei_st, ei_ts, offs_st, offs_ts,
                                        cur_t, cur_s, adj_st, adj_ts, NE, EB);

  // ---------------- Layer 0: gathers + all dropout masks (co-scheduled) ----
  gather2m_mean_h<<<2 * GGB + MASK_BLKS, 256, 0, stream>>>(
      xs0h, offs_st, adj_st, B0h, xt0h, offs_ts, adj_ts, B1h, masks, NTGT, GGB);

  // new_t -> B2h (mask slice 0 = FOLD[1]);  new_s -> B0h (slice 1 = FOLD[0])
  gemm_dual_mfma<<<GBLK, 256, 0, stream>>>(
      B0h, xt0h, wt0, wt1, b_st, (const uint2*)(masks), B2h, NTGT);
  gemm_dual_mfma<<<GBLK, 256, 0, stream>>>(
      B1h, xs0h, wt2, wt3, b_ts, (const uint2*)(masks + MASK_DW_PER), B0h, NSRC);

  // ---------------- Layer 1 (source side only; target side dead) ----------
  gather_mean_h<<<GGB, 256, 0, stream>>>(B2h, offs_ts, adj_ts, B1h, NSRC);
  gemm_dual_mfma<<<GBLK, 256, 0, stream>>>(
      B1h, B0h, wt4, wt5, b_ts + HID, (const uint2*)(masks + 2 * MASK_DW_PER),
      B2h, NSRC);

  out_gemm_h<<<(NSRC + 15) / 16, 256, 0, stream>>>(B2h, Wout, bout, out, NSRC);
}

// Round 10
// 466.077 us; speedup vs baseline: 8.7947x; 1.0956x over previous
//
#include <hip/hip_runtime.h>
#include <stdint.h>

// Problem constants (fixed by reference)
#define NSRC 50000
#define NTGT 50000
#define NE   320000
#define DIN  256
#define HID  256
#define DOUT 16

#define GBM 64
#define GBLK ((NSRC + GBM - 1) / GBM)      // 782 gemm blocks
#define MASK_DW_PER (GBLK * 512)           // 400384 mask dwords per gemm
#define MASK_BLKS (3 * MASK_DW_PER / 256)  // 4692 mask-gen blocks

typedef __attribute__((ext_vector_type(8))) short bf16x8;
typedef __attribute__((ext_vector_type(4))) float f32x4;

// ---------------------------------------------------------------------------
// bf16 <-> f32 (RNE, matches HW/XLA rounding)
// ---------------------------------------------------------------------------
__device__ inline ushort f2b(float f) {
  uint32_t u = __float_as_uint(f);
  return (ushort)((u + 0x7FFFu + ((u >> 16) & 1u)) >> 16);
}
__device__ inline float b2f(ushort h) { return __uint_as_float(((uint32_t)h) << 16); }

// ---------------------------------------------------------------------------
// Async global->LDS 16B copy: lane deposits 16 B at lds_base + lane*16.
// ---------------------------------------------------------------------------
typedef __attribute__((address_space(3))) uint32_t lds_u32_t;
typedef const __attribute__((address_space(1))) uint32_t glb_u32_t;
__device__ __forceinline__ void ld_lds16(const ushort* g, ushort* lds) {
  __builtin_amdgcn_global_load_lds((glb_u32_t*)g, (lds_u32_t*)lds, 16, 0, 0);
}

// ---------------------------------------------------------------------------
// Threefry-2x32 (exact JAX: 20 rounds, 5 key injections) — verified R2
// ---------------------------------------------------------------------------
__host__ __device__ constexpr uint64_t tf2x32(uint32_t k0, uint32_t k1,
                                              uint32_t x0, uint32_t x1) {
  uint32_t ks2 = k0 ^ k1 ^ 0x1BD11BDAu;
  x0 += k0; x1 += k1;
#define TF_ROT(x, r) (((x) << (r)) | ((x) >> (32 - (r))))
#define TF_RND(r) { x0 += x1; x1 = TF_ROT(x1, r) ^ x0; }
  TF_RND(13) TF_RND(15) TF_RND(26) TF_RND(6)
  x0 += k1;  x1 += ks2 + 1u;
  TF_RND(17) TF_RND(29) TF_RND(16) TF_RND(24)
  x0 += ks2; x1 += k0 + 2u;
  TF_RND(13) TF_RND(15) TF_RND(26) TF_RND(6)
  x0 += k0;  x1 += k1 + 3u;
  TF_RND(17) TF_RND(29) TF_RND(16) TF_RND(24)
  x0 += k1;  x1 += ks2 + 4u;
  TF_RND(13) TF_RND(15) TF_RND(26) TF_RND(6)
  x0 += ks2; x1 += k0 + 5u;
#undef TF_RND
#undef TF_ROT
  return (uint64_t(x0) << 32) | uint64_t(x1);
}

constexpr uint64_t FOLD[4] = {
  tf2x32(0u, 42u, 0u, 0u),
  tf2x32(0u, 42u, 0u, 1u),
  tf2x32(0u, 42u, 0u, 2u),
  tf2x32(0u, 42u, 0u, 3u),
};

// ---------------------------------------------------------------------------
// Pure f32->bf16 conversion (both inputs, one launch). Memory-bound.
// ---------------------------------------------------------------------------
__global__ __launch_bounds__(256) void cvt2_f32_bf16(const float* __restrict__ a,
                                                     const float* __restrict__ b,
                                                     ushort* __restrict__ oa,
                                                     ushort* __restrict__ ob,
                                                     int n4, int nbPer) {
  int blk = blockIdx.x;
  const float* in = blk < nbPer ? a : b;
  ushort* out = blk < nbPer ? oa : ob;
  int i = (blk % nbPer) * 256 + threadIdx.x;
  if (i >= n4) return;
  float4 v = ((const float4*)in)[i];
  ushort4 o;
  o.x = f2b(v.x); o.y = f2b(v.y); o.z = f2b(v.z); o.w = f2b(v.w);
  ((ushort4*)out)[i] = o;
}

// ---------------------------------------------------------------------------
// Dropout keep-mask word for mask-dword index d (bit layout mirrors the gemm
// epilogue; verified bit-identical R8/R9). Keep test: bits>>9 < 7549747
// (== 0.9f * 2^23, exact).
// ---------------------------------------------------------------------------
__device__ __forceinline__ void mask_word(uint32_t* __restrict__ masks, int d) {
  int g = d / MASK_DW_PER;                            // 0..2
  int w = d - g * MASK_DW_PER;
  int gt = w >> 1, half = w & 1;
  int gblk = gt >> 8, gtid = gt & 255;
  int wave = gtid >> 6, lane = gtid & 63;
  int q = lane >> 4, r = lane & 15;
  uint64_t fk = (g == 0) ? FOLD[1] : (g == 1 ? FOLD[0] : FOLD[2]);
  uint32_t kk0 = (uint32_t)(fk >> 32), kk1 = (uint32_t)fk;
  int mbase = gblk * GBM;
  uint32_t mword = 0;
#pragma unroll
  for (int bb = 0; bb < 32; ++bb) {
    int s = half * 32 + bb;
    int si = s >> 4, se = (s >> 2) & 3, sj = s & 3;
    uint32_t rowg = (uint32_t)(mbase + si * 16 + q * 4 + se);
    uint32_t colg = (uint32_t)(wave * 64 + sj * 16 + r);
    uint64_t rr = tf2x32(kk0, kk1, 0u, rowg * 256u + colg);
    uint32_t bits = (uint32_t)(rr >> 32) ^ (uint32_t)rr;
    mword |= (((bits >> 9) < 7549747u) ? 1u : 0u) << bb;
  }
  masks[d] = mword;
}

struct W6 {
  const float* s[6];
  ushort* d[6];
};
// W fp32 [256 k][256 n] -> Wt bf16 [256 n][256 k]; 16 blocks per weight
__global__ __launch_bounds__(256) void wcvt_t6(W6 p) {
  __shared__ ushort tile[64][65];
  int w = blockIdx.x >> 4;
  const float* W = p.s[w];
  ushort* Wt = p.d[w];
  int t = threadIdx.x;
  int ktile = (blockIdx.x >> 2) & 3, ntile = blockIdx.x & 3;
#pragma unroll
  for (int rep = 0; rep < 16; ++rep) {
    int lin = rep * 256 + t;
    int kk = lin >> 6, nn = lin & 63;
    tile[nn][kk] = f2b(W[(size_t)(ktile * 64 + kk) * 256 + ntile * 64 + nn]);
  }
  __syncthreads();
#pragma unroll
  for (int rep = 0; rep < 16; ++rep) {
    int lin = rep * 256 + t;
    int nn = lin >> 6, kk = lin & 63;
    Wt[(size_t)(ntile * 64 + nn) * 256 + ktile * 64 + kk] = tile[nn][kk];
  }
}

// ---------------------------------------------------------------------------
// CSR build (two-level scan, verified R6)
// ---------------------------------------------------------------------------
__global__ __launch_bounds__(256) void csr_hist2(const int* __restrict__ ei_a,
                                                 const int* __restrict__ ei_b,
                                                 int* __restrict__ cur_a,
                                                 int* __restrict__ cur_b,
                                                 int nE, int nbPer) {
  int blk = blockIdx.x;
  const int* ei = blk < nbPer ? ei_a : ei_b;
  int* cur = blk < nbPer ? cur_a : cur_b;
  int e = (blk % nbPer) * 256 + threadIdx.x;
  if (e < nE) atomicAdd(cur + ei[nE + e], 1);
}

#define SB 1024
__global__ __launch_bounds__(SB) void scan_partial(const int* __restrict__ cur_a,
                                                   const int* __restrict__ cur_b,
                                                   int* __restrict__ bsum,
                                                   int n, int nbPer) {
  __shared__ int red[SB];
  int b = blockIdx.x;
  const int* cnt = b < nbPer ? cur_a : cur_b;
  int i = (b % nbPer) * SB + threadIdx.x;
  red[threadIdx.x] = (i < n) ? cnt[i] : 0;
  __syncthreads();
  for (int d = SB / 2; d > 0; d >>= 1) {
    if (threadIdx.x < d) red[threadIdx.x] += red[threadIdx.x + d];
    __syncthreads();
  }
  if (threadIdx.x == 0) bsum[b] = red[0];
}

__global__ __launch_bounds__(128) void scan_base(int* __restrict__ bsum, int nbPer) {
  __shared__ int buf[2][64];
  int half = threadIdx.x >> 6;
  int t = threadIdx.x & 63;
  buf[half][t] = (t < nbPer) ? bsum[half * nbPer + t] : 0;
  __syncthreads();
  for (int d = 1; d < 64; d <<= 1) {
    int v = (t >= d) ? buf[half][t - d] : 0;
    __syncthreads();
    buf[half][t] += v;
    __syncthreads();
  }
  if (t < nbPer) bsum[half * nbPer + t] = (t == 0) ? 0 : buf[half][t - 1];
}

__global__ __launch_bounds__(SB) void scan_final(int* __restrict__ cur_a,
                                                 int* __restrict__ cur_b,
                                                 int* __restrict__ offs_a,
                                                 int* __restrict__ offs_b,
                                                 const int* __restrict__ bsum,
                                                 int n, int nbPer) {
  __shared__ int part[SB];
  int b = blockIdx.x;
  bool first = b < nbPer;
  int* cur = first ? cur_a : cur_b;
  int* offs = first ? offs_a : offs_b;
  int i = (b % nbPer) * SB + threadIdx.x;
  int v = (i < n) ? cur[i] : 0;
  part[threadIdx.x] = v;
  __syncthreads();
  for (int d = 1; d < SB; d <<= 1) {
    int tv = (threadIdx.x >= d) ? part[threadIdx.x - d] : 0;
    __syncthreads();
    part[threadIdx.x] += tv;
    __syncthreads();
  }
  int excl = part[threadIdx.x] - v + bsum[b];
  if (i < n) {
    offs[i] = excl;
    cur[i] = 0;
  }
  if (i == n - 1) offs[n] = excl + v;
}

__global__ __launch_bounds__(256) void csr_fill2(const int* __restrict__ ei_a,
                                                 const int* __restrict__ ei_b,
                                                 const int* __restrict__ offs_a,
                                                 const int* __restrict__ offs_b,
                                                 int* __restrict__ cur_a,
                                                 int* __restrict__ cur_b,
                                                 int* __restrict__ adj_a,
                                                 int* __restrict__ adj_b,
                                                 int nE, int nbPer) {
  int blk = blockIdx.x;
  bool first = blk < nbPer;
  const int* ei = first ? ei_a : ei_b;
  const int* offs = first ? offs_a : offs_b;
  int* cur = first ? cur_a : cur_b;
  int* adj = first ? adj_a : adj_b;
  int e = (blk % nbPer) * 256 + threadIdx.x;
  if (e >= nE) return;
  int dst = ei[nE + e];
  int pos = atomicAdd(cur + dst, 1);
  adj[offs[dst] + pos] = ei[e];
}

// ---------------------------------------------------------------------------
// Segment-mean gather, bf16 in/out, fp32 accumulate. One wave per row.
// R9 post-mortem: 4x edge unroll for MLP (4 row-loads in flight before the
// dependent adds). Adds stay in the original sequential order (e,e+1,e+2,e+3)
// -> results bit-identical to R9.
// ---------------------------------------------------------------------------
__device__ __forceinline__ void gather_row(const ushort* __restrict__ x,
                                           const int* __restrict__ offs,
                                           const int* __restrict__ adj,
                                           ushort* __restrict__ m,
                                           int row, int lane) {
  int start = offs[row], end = offs[row + 1];
  float a0 = 0.f, a1 = 0.f, a2 = 0.f, a3 = 0.f;
  int e = start;
  for (; e + 3 < end; e += 4) {
    int s0 = adj[e], s1 = adj[e + 1], s2 = adj[e + 2], s3 = adj[e + 3];
    ushort4 v0 = *(const ushort4*)(x + (size_t)s0 * DIN + lane * 4);
    ushort4 v1 = *(const ushort4*)(x + (size_t)s1 * DIN + lane * 4);
    ushort4 v2 = *(const ushort4*)(x + (size_t)s2 * DIN + lane * 4);
    ushort4 v3 = *(const ushort4*)(x + (size_t)s3 * DIN + lane * 4);
    a0 += b2f(v0.x); a1 += b2f(v0.y); a2 += b2f(v0.z); a3 += b2f(v0.w);
    a0 += b2f(v1.x); a1 += b2f(v1.y); a2 += b2f(v1.z); a3 += b2f(v1.w);
    a0 += b2f(v2.x); a1 += b2f(v2.y); a2 += b2f(v2.z); a3 += b2f(v2.w);
    a0 += b2f(v3.x); a1 += b2f(v3.y); a2 += b2f(v3.z); a3 += b2f(v3.w);
  }
  for (; e < end; ++e) {
    int s = adj[e];
    ushort4 v = *(const ushort4*)(x + (size_t)s * DIN + lane * 4);
    a0 += b2f(v.x); a1 += b2f(v.y); a2 += b2f(v.z); a3 += b2f(v.w);
  }
  float inv = 1.0f / fmaxf((float)(end - start), 1.0f);
  ushort4 o;
  o.x = f2b(a0 * inv); o.y = f2b(a1 * inv); o.z = f2b(a2 * inv); o.w = f2b(a3 * inv);
  *(ushort4*)(m + (size_t)row * DIN + lane * 4) = o;
}

__global__ __launch_bounds__(256) void gather_mean_h(const ushort* __restrict__ x,
                                                     const int* __restrict__ offs,
                                                     const int* __restrict__ adj,
                                                     ushort* __restrict__ m,
                                                     int nRows) {
  int row = blockIdx.x * 4 + (threadIdx.x >> 6);
  if (row >= nRows) return;
  gather_row(x, offs, adj, m, row, threadIdx.x & 63);
}

// gather2m: both L0 relations + ALL dropout-mask generation in one launch.
// R9 post-mortem: tail-appended mask blocks ran AFTER the gathers (dispatch
// order) -> sum not max. Fix: bijective block swizzle blk'=(blk*97)%T spreads
// mask blocks (15.8%) uniformly so every CU co-schedules latency-bound gather
// waves with VALU-bound mask waves (m114: time = max).
__global__ __launch_bounds__(256) void gather2m_mean_h(
    const ushort* __restrict__ xa, const int* __restrict__ offsa,
    const int* __restrict__ adja, ushort* __restrict__ ma,
    const ushort* __restrict__ xb, const int* __restrict__ offsb,
    const int* __restrict__ adjb, ushort* __restrict__ mb,
    uint32_t* __restrict__ masks, int nRows, int nbPer) {
  const int T = 2 * nbPer + MASK_BLKS;
  int blk = (int)(((long long)blockIdx.x * 97) % T);
  if (blk >= 2 * nbPer) {  // dropout-mask generation block
    mask_word(masks, (blk - 2 * nbPer) * 256 + threadIdx.x);
    return;
  }
  bool first = blk < nbPer;
  int row = (blk % nbPer) * 4 + (threadIdx.x >> 6);
  if (row >= nRows) return;
  if (first) gather_row(xa, offsa, adja, ma, row, threadIdx.x & 63);
  else       gather_row(xb, offsb, adjb, mb, row, threadIdx.x & 63);
}

// ---------------------------------------------------------------------------
// MFMA dual GEMM v3 (verified R8): C = dropout(leaky(A1@W1 + A2@W2 + bias)).
// Masks precomputed; async global_load_lds staging; 40KB LDS; bounds (256,4).
// ---------------------------------------------------------------------------
__global__ __launch_bounds__(256, 4) void gemm_dual_mfma(
    const ushort* __restrict__ A1, const ushort* __restrict__ A2,
    const ushort* __restrict__ W1t, const ushort* __restrict__ W2t,
    const float* __restrict__ bias, const uint2* __restrict__ mk,
    ushort* __restrict__ C, int M) {
  __shared__ ushort sA[2][GBM * 32];    // 4 KB per buffer
  __shared__ ushort sB[2][HID * 32];    // 16 KB per buffer
  const int tid = threadIdx.x;
  const int wave = tid >> 6, lane = tid & 63;
  const int q = lane >> 4, r = lane & 15;
  const int mbase = blockIdx.x * GBM;

  const uint2 km = mk[blockIdx.x * 256 + tid];  // issued early, hidden by K-loop

  f32x4 acc[4][4] = {};

  const int arow = tid >> 2;        // 0..63
  const int akc = (tid & 3) * 8;    // short offset 0,8,16,24
  const int agrow = min(mbase + arow, M - 1);
  const ushort* a1p = A1 + (size_t)agrow * DIN + akc;
  const ushort* a2p = A2 + (size_t)agrow * DIN + akc;
  const ushort* w1b = W1t + (size_t)arow * DIN + akc;
  const ushort* w2b = W2t + (size_t)arow * DIN + akc;
  ushort* ldsA0 = &sA[0][wave * 512];
  ushort* ldsA1 = &sA[1][wave * 512];

#pragma unroll
  for (int t = 0; t < 8; ++t) {
    const int kt = t * 32;
    __syncthreads();  // prior iter's LDS reads done before DMA overwrites
    ld_lds16(a1p + kt, ldsA0);
    ld_lds16(a2p + kt, ldsA1);
#pragma unroll
    for (int c = 0; c < 4; ++c) {
      ld_lds16(w1b + c * (64 * DIN) + kt, &sB[0][c * 2048 + wave * 512]);
      ld_lds16(w2b + c * (64 * DIN) + kt, &sB[1][c * 2048 + wave * 512]);
    }
    __syncthreads();  // drains vmcnt(0): DMA complete
#pragma unroll
    for (int ph = 0; ph < 2; ++ph) {
      bf16x8 af[4], bfr[4];
#pragma unroll
      for (int i = 0; i < 4; ++i)
        af[i] = *(const bf16x8*)&sA[ph][(i * 16 + r) * 32 + q * 8];
#pragma unroll
      for (int j = 0; j < 4; ++j)
        bfr[j] = *(const bf16x8*)&sB[ph][(wave * 64 + j * 16 + r) * 32 + q * 8];
#pragma unroll
      for (int i = 0; i < 4; ++i)
#pragma unroll
        for (int j = 0; j < 4; ++j)
          acc[i][j] = __builtin_amdgcn_mfma_f32_16x16x32_bf16(af[i], bfr[j],
                                                              acc[i][j], 0, 0, 0);
    }
  }

  // Epilogue: bias + leaky + masked dropout scale + bf16 store
  float bj[4];
#pragma unroll
  for (int j = 0; j < 4; ++j) bj[j] = bias[wave * 64 + j * 16 + r];
#pragma unroll
  for (int i = 0; i < 4; ++i) {
#pragma unroll
    for (int e = 0; e < 4; ++e) {
      int rowg = mbase + i * 16 + q * 4 + e;
      if (rowg >= M) continue;
#pragma unroll
      for (int j = 0; j < 4; ++j) {
        const int s = i * 16 + e * 4 + j;
        int colg = wave * 64 + j * 16 + r;
        float v = acc[i][j][e] + bj[j];
        v = v >= 0.0f ? v : 0.01f * v;
        uint32_t keep = ((s < 32 ? km.x >> s : km.y >> (s - 32)) & 1u);
        v = keep ? v * (1.0f / 0.9f) : 0.0f;
        C[(size_t)rowg * HID + colg] = f2b(v);
      }
    }
  }
}

// ---------------------------------------------------------------------------
// Final projection: [M,256] bf16 @ [256,16] fp32 + bout -> fp32
// ---------------------------------------------------------------------------
__global__ __launch_bounds__(256) void out_gemm_h(const ushort* __restrict__ X,
                                                  const float* __restrict__ Wout,
                                                  const float* __restrict__ bout,
                                                  float* __restrict__ C, int M) {
  __shared__ float sW[DIN * DOUT];
  int tid = threadIdx.x;
#pragma unroll
  for (int i = 0; i < (DIN * DOUT) / 256; ++i) sW[i * 256 + tid] = Wout[i * 256 + tid];
  __syncthreads();
  int rr = tid >> 4, c = tid & 15;
  int row = blockIdx.x * 16 + rr;
  if (row >= M) return;
  float acc = bout[c];
  const ushort* xp = X + (size_t)row * DIN;
  for (int k = 0; k < DIN; k += 8) {
    uint4 u = *(const uint4*)(xp + k);
    const ushort* us = (const ushort*)&u;
#pragma unroll
    for (int t = 0; t < 8; ++t) acc += b2f(us[t]) * sW[(k + t) * DOUT + c];
  }
  C[(size_t)row * DOUT + c] = acc;
}

// ---------------------------------------------------------------------------
// Workspace (~138 MB < 154 MB proven safe)
// ---------------------------------------------------------------------------
extern "C" void kernel_launch(void* const* d_in, const int* in_sizes, int n_in,
                              void* d_out, int out_size, void* d_ws, size_t ws_size,
                              hipStream_t stream) {
  const float* x_source = (const float*)d_in[0];
  const float* x_target = (const float*)d_in[1];
  const int* ei_st = (const int*)d_in[2];
  const int* ei_ts = (const int*)d_in[3];
  const float* Wl_st = (const float*)d_in[4];
  const float* Wr_st = (const float*)d_in[5];
  const float* b_st  = (const float*)d_in[6];
  const float* Wl_ts = (const float*)d_in[7];
  const float* Wr_ts = (const float*)d_in[8];
  const float* b_ts  = (const float*)d_in[9];
  const float* Wout  = (const float*)d_in[10];
  const float* bout  = (const float*)d_in[11];
  float* out = (float*)d_out;

  const size_t F = (size_t)NSRC * DIN;  // 12.8M elements
  const size_t WM = (size_t)DIN * HID;  // 65536
  const int nbScan = (NSRC + SB - 1) / SB;  // 49 (NSRC==NTGT)
  const size_t intCount = (NTGT + 1) + (NSRC + 1) + 2 * NE + NTGT + NSRC +
                          2 * nbScan + 3 * MASK_DW_PER;
  const size_t need = (5 * F + 6 * WM) * sizeof(ushort) + intCount * sizeof(int);
  if (ws_size < need) return;

  ushort* xs0h = (ushort*)d_ws;
  ushort* xt0h = xs0h + F;
  ushort* B0h  = xt0h + F;
  ushort* B1h  = B0h + F;
  ushort* B2h  = B1h + F;
  ushort* wt0  = B2h + F;       // Wl_st[0]^T
  ushort* wt1  = wt0 + WM;      // Wr_st[0]^T
  ushort* wt2  = wt1 + WM;      // Wl_ts[0]^T
  ushort* wt3  = wt2 + WM;      // Wr_ts[0]^T
  ushort* wt4  = wt3 + WM;      // Wl_ts[1]^T
  ushort* wt5  = wt4 + WM;      // Wr_ts[1]^T
  int* ip      = (int*)(wt5 + WM);
  int* offs_st = ip;
  int* offs_ts = offs_st + NTGT + 1;
  int* adj_st  = offs_ts + NSRC + 1;
  int* adj_ts  = adj_st + NE;
  int* cur_t   = adj_ts + NE;        // [NTGT] + [NSRC] adjacent for one memset
  int* cur_s   = cur_t + NTGT;
  int* bsum    = cur_s + NSRC;       // [2*nbScan]
  uint32_t* masks = (uint32_t*)(bsum + 2 * nbScan);  // [3*MASK_DW_PER]

  const int EB = (NE + 255) / 256;
  const int CB = (int)(F / 4 + 255) / 256;  // cvt blocks per input (12500)
  const int GGB = (int)((NTGT / 4));        // gather blocks per relation (12500)

  // ---- Convert inputs to bf16 ----
  cvt2_f32_bf16<<<2 * CB, 256, 0, stream>>>(x_source, x_target, xs0h, xt0h,
                                            (int)(F / 4), CB);
  W6 wb;
  wb.s[0] = Wl_st;      wb.d[0] = wt0;
  wb.s[1] = Wr_st;      wb.d[1] = wt1;
  wb.s[2] = Wl_ts;      wb.d[2] = wt2;
  wb.s[3] = Wr_ts;      wb.d[3] = wt3;
  wb.s[4] = Wl_ts + WM; wb.d[4] = wt4;
  wb.s[5] = Wr_ts + WM; wb.d[5] = wt5;
  wcvt_t6<<<96, 256, 0, stream>>>(wb);

  // ---- Build both CSRs concurrently ----
  hipMemsetAsync(cur_t, 0, (NTGT + NSRC) * sizeof(int), stream);
  csr_hist2<<<2 * EB, 256, 0, stream>>>(ei_st, ei_ts, cur_t, cur_s, NE, EB);
  scan_partial<<<2 * nbScan, SB, 0, stream>>>(cur_t, cur_s, bsum, NTGT, nbScan);
  scan_base<<<1, 128, 0, stream>>>(bsum, nbScan);
  scan_final<<<2 * nbScan, SB, 0, stream>>>(cur_t, cur_s, offs_st, offs_ts,
                                            bsum, NTGT, nbScan);
  csr_fill2<<<2 * EB, 256, 0, stream>>>(ei_st, ei_ts, offs_st, offs_ts,
                                        cur_t, cur_s, adj_st, adj_ts, NE, EB);

  // ---------------- Layer 0: gathers + all dropout masks (interleaved) ----
  gather2m_mean_h<<<2 * GGB + MASK_BLKS, 256, 0, stream>>>(
      xs0h, offs_st, adj_st, B0h, xt0h, offs_ts, adj_ts, B1h, masks, NTGT, GGB);

  // new_t -> B2h (mask slice 0 = FOLD[1]);  new_s -> B0h (slice 1 = FOLD[0])
  gemm_dual_mfma<<<GBLK, 256, 0, stream>>>(
      B0h, xt0h, wt0, wt1, b_st, (const uint2*)(masks), B2h, NTGT);
  gemm_dual_mfma<<<GBLK, 256, 0, stream>>>(
      B1h, xs0h, wt2, wt3, b_ts, (const uint2*)(masks + MASK_DW_PER), B0h, NSRC);

  // ---------------- Layer 1 (source side only; target side dead) ----------
  gather_mean_h<<<GGB, 256, 0, stream>>>(B2h, offs_ts, adj_ts, B1h, NSRC);
  gemm_dual_mfma<<<GBLK, 256, 0, stream>>>(
      B1h, B0h, wt4, wt5, b_ts + HID, (const uint2*)(masks + 2 * MASK_DW_PER),
      B2h, NSRC);

  out_gemm_h<<<(NSRC + 15) / 16, 256, 0, stream>>>(B2h, Wout, bout, out, NSRC);
}

// Round 11
// 446.256 us; speedup vs baseline: 9.1854x; 1.0444x over previous
//
#include <hip/hip_runtime.h>
#include <stdint.h>

// Problem constants (fixed by reference)
#define NSRC 50000
#define NTGT 50000
#define NE   320000
#define DIN  256
#define HID  256
#define DOUT 16

#define GBM 64
#define GBLK ((NSRC + GBM - 1) / GBM)      // 782 gemm blocks
#define MASK_DW_PER (GBLK * 512)           // 400384 mask dwords per gemm
#define MASK_BLKS (3 * MASK_DW_PER / 256)  // 4692 mask-gen blocks

typedef __attribute__((ext_vector_type(8))) short bf16x8;
typedef __attribute__((ext_vector_type(4))) float f32x4;

// ---------------------------------------------------------------------------
// bf16 <-> f32 (RNE, matches HW/XLA rounding)
// ---------------------------------------------------------------------------
__device__ inline ushort f2b(float f) {
  uint32_t u = __float_as_uint(f);
  return (ushort)((u + 0x7FFFu + ((u >> 16) & 1u)) >> 16);
}
__device__ inline float b2f(ushort h) { return __uint_as_float(((uint32_t)h) << 16); }

// ---------------------------------------------------------------------------
// Async global->LDS 16B copy: lane deposits 16 B at lds_base + lane*16.
// ---------------------------------------------------------------------------
typedef __attribute__((address_space(3))) uint32_t lds_u32_t;
typedef const __attribute__((address_space(1))) uint32_t glb_u32_t;
__device__ __forceinline__ void ld_lds16(const ushort* g, ushort* lds) {
  __builtin_amdgcn_global_load_lds((glb_u32_t*)g, (lds_u32_t*)lds, 16, 0, 0);
}

// ---------------------------------------------------------------------------
// Threefry-2x32 (exact JAX: 20 rounds, 5 key injections) — verified R2
// ---------------------------------------------------------------------------
__host__ __device__ constexpr uint64_t tf2x32(uint32_t k0, uint32_t k1,
                                              uint32_t x0, uint32_t x1) {
  uint32_t ks2 = k0 ^ k1 ^ 0x1BD11BDAu;
  x0 += k0; x1 += k1;
#define TF_ROT(x, r) (((x) << (r)) | ((x) >> (32 - (r))))
#define TF_RND(r) { x0 += x1; x1 = TF_ROT(x1, r) ^ x0; }
  TF_RND(13) TF_RND(15) TF_RND(26) TF_RND(6)
  x0 += k1;  x1 += ks2 + 1u;
  TF_RND(17) TF_RND(29) TF_RND(16) TF_RND(24)
  x0 += ks2; x1 += k0 + 2u;
  TF_RND(13) TF_RND(15) TF_RND(26) TF_RND(6)
  x0 += k0;  x1 += k1 + 3u;
  TF_RND(17) TF_RND(29) TF_RND(16) TF_RND(24)
  x0 += k1;  x1 += ks2 + 4u;
  TF_RND(13) TF_RND(15) TF_RND(26) TF_RND(6)
  x0 += ks2; x1 += k0 + 5u;
#undef TF_RND
#undef TF_ROT
  return (uint64_t(x0) << 32) | uint64_t(x1);
}

constexpr uint64_t FOLD[4] = {
  tf2x32(0u, 42u, 0u, 0u),
  tf2x32(0u, 42u, 0u, 1u),
  tf2x32(0u, 42u, 0u, 2u),
  tf2x32(0u, 42u, 0u, 3u),
};

// ---------------------------------------------------------------------------
// Dropout keep-mask word for mask-dword index d (bit layout mirrors the gemm
// epilogue; verified bit-identical R8-R10). Keep: bits>>9 < 7549747
// (== 0.9f * 2^23, exact).
// ---------------------------------------------------------------------------
__device__ __forceinline__ void mask_word(uint32_t* __restrict__ masks, int d) {
  int g = d / MASK_DW_PER;                            // 0..2
  int w = d - g * MASK_DW_PER;
  int gt = w >> 1, half = w & 1;
  int gblk = gt >> 8, gtid = gt & 255;
  int wave = gtid >> 6, lane = gtid & 63;
  int q = lane >> 4, r = lane & 15;
  uint64_t fk = (g == 0) ? FOLD[1] : (g == 1 ? FOLD[0] : FOLD[2]);
  uint32_t kk0 = (uint32_t)(fk >> 32), kk1 = (uint32_t)fk;
  int mbase = gblk * GBM;
  uint32_t mword = 0;
#pragma unroll
  for (int bb = 0; bb < 32; ++bb) {
    int s = half * 32 + bb;
    int si = s >> 4, se = (s >> 2) & 3, sj = s & 3;
    uint32_t rowg = (uint32_t)(mbase + si * 16 + q * 4 + se);
    uint32_t colg = (uint32_t)(wave * 64 + sj * 16 + r);
    uint64_t rr = tf2x32(kk0, kk1, 0u, rowg * 256u + colg);
    uint32_t bits = (uint32_t)(rr >> 32) ^ (uint32_t)rr;
    mword |= (((bits >> 9) < 7549747u) ? 1u : 0u) << bb;
  }
  masks[d] = mword;
}

// ---------------------------------------------------------------------------
// prep_kernel: ALL independent front work in one swizzled launch:
//   [0, 25000)        f32->bf16 conversion of both inputs  (memory-bound)
//   [25000, 25096)    6 weight transpose+converts           (memory-bound)
//   [25096, 27596)    2 CSR histograms                      (atomic-bound)
//   [27596, 32288)    3 dropout masks                       (VALU-bound)
// Swizzle (*97 mod T) interleaves classes so mask VALU hides under the
// memory/atomic stalls of the other classes (m114: time = max, not sum).
// ---------------------------------------------------------------------------
#define NB_CVT  25000
#define NB_W    96
#define NB_HIST 2500
#define PREP_T  (NB_CVT + NB_W + NB_HIST + MASK_BLKS)  // 32288

struct PrepArgs {
  const float *xs, *xt;
  ushort *oxs, *oxt;
  const float* wsrc[6];
  ushort* wdst[6];
  const int *ei_a, *ei_b;
  int *cur_a, *cur_b;
  uint32_t* masks;
};

__global__ __launch_bounds__(256) void prep_kernel(PrepArgs p) {
  __shared__ ushort tile[64][65];
  int blk = (int)(((long long)blockIdx.x * 97) % PREP_T);
  int tid = threadIdx.x;
  if (blk < NB_CVT) {  // input conversion
    const float* in = blk < (NB_CVT / 2) ? p.xs : p.xt;
    ushort* out = blk < (NB_CVT / 2) ? p.oxs : p.oxt;
    int i = (blk % (NB_CVT / 2)) * 256 + tid;
    float4 v = ((const float4*)in)[i];
    ushort4 o;
    o.x = f2b(v.x); o.y = f2b(v.y); o.z = f2b(v.z); o.w = f2b(v.w);
    ((ushort4*)out)[i] = o;
    return;
  }
  blk -= NB_CVT;
  if (blk < NB_W) {  // weight transpose: fp32 [k][n] -> bf16 [n][k]
    const float* W = p.wsrc[blk >> 4];
    ushort* Wt = p.wdst[blk >> 4];
    int ktile = (blk >> 2) & 3, ntile = blk & 3;
#pragma unroll
    for (int rep = 0; rep < 16; ++rep) {
      int lin = rep * 256 + tid;
      int kk = lin >> 6, nn = lin & 63;
      tile[nn][kk] = f2b(W[(size_t)(ktile * 64 + kk) * 256 + ntile * 64 + nn]);
    }
    __syncthreads();
#pragma unroll
    for (int rep = 0; rep < 16; ++rep) {
      int lin = rep * 256 + tid;
      int nn = lin >> 6, kk = lin & 63;
      Wt[(size_t)(ntile * 64 + nn) * 256 + ktile * 64 + kk] = tile[nn][kk];
    }
    return;
  }
  blk -= NB_W;
  if (blk < NB_HIST) {  // CSR histogram
    const int* ei = blk < (NB_HIST / 2) ? p.ei_a : p.ei_b;
    int* cur = blk < (NB_HIST / 2) ? p.cur_a : p.cur_b;
    int e = (blk % (NB_HIST / 2)) * 256 + tid;
    if (e < NE) atomicAdd(cur + ei[NE + e], 1);
    return;
  }
  blk -= NB_HIST;
  mask_word(p.masks, blk * 256 + tid);
}

// ---------------------------------------------------------------------------
// CSR scan + fill (two-level scan, verified R6)
// ---------------------------------------------------------------------------
#define SB 1024
__global__ __launch_bounds__(SB) void scan_partial(const int* __restrict__ cur_a,
                                                   const int* __restrict__ cur_b,
                                                   int* __restrict__ bsum,
                                                   int n, int nbPer) {
  __shared__ int red[SB];
  int b = blockIdx.x;
  const int* cnt = b < nbPer ? cur_a : cur_b;
  int i = (b % nbPer) * SB + threadIdx.x;
  red[threadIdx.x] = (i < n) ? cnt[i] : 0;
  __syncthreads();
  for (int d = SB / 2; d > 0; d >>= 1) {
    if (threadIdx.x < d) red[threadIdx.x] += red[threadIdx.x + d];
    __syncthreads();
  }
  if (threadIdx.x == 0) bsum[b] = red[0];
}

__global__ __launch_bounds__(128) void scan_base(int* __restrict__ bsum, int nbPer) {
  __shared__ int buf[2][64];
  int half = threadIdx.x >> 6;
  int t = threadIdx.x & 63;
  buf[half][t] = (t < nbPer) ? bsum[half * nbPer + t] : 0;
  __syncthreads();
  for (int d = 1; d < 64; d <<= 1) {
    int v = (t >= d) ? buf[half][t - d] : 0;
    __syncthreads();
    buf[half][t] += v;
    __syncthreads();
  }
  if (t < nbPer) bsum[half * nbPer + t] = (t == 0) ? 0 : buf[half][t - 1];
}

__global__ __launch_bounds__(SB) void scan_final(int* __restrict__ cur_a,
                                                 int* __restrict__ cur_b,
                                                 int* __restrict__ offs_a,
                                                 int* __restrict__ offs_b,
                                                 const int* __restrict__ bsum,
                                                 int n, int nbPer) {
  __shared__ int part[SB];
  int b = blockIdx.x;
  bool first = b < nbPer;
  int* cur = first ? cur_a : cur_b;
  int* offs = first ? offs_a : offs_b;
  int i = (b % nbPer) * SB + threadIdx.x;
  int v = (i < n) ? cur[i] : 0;
  part[threadIdx.x] = v;
  __syncthreads();
  for (int d = 1; d < SB; d <<= 1) {
    int tv = (threadIdx.x >= d) ? part[threadIdx.x - d] : 0;
    __syncthreads();
    part[threadIdx.x] += tv;
    __syncthreads();
  }
  int excl = part[threadIdx.x] - v + bsum[b];
  if (i < n) {
    offs[i] = excl;
    cur[i] = 0;
  }
  if (i == n - 1) offs[n] = excl + v;
}

__global__ __launch_bounds__(256) void csr_fill2(const int* __restrict__ ei_a,
                                                 const int* __restrict__ ei_b,
                                                 const int* __restrict__ offs_a,
                                                 const int* __restrict__ offs_b,
                                                 int* __restrict__ cur_a,
                                                 int* __restrict__ cur_b,
                                                 int* __restrict__ adj_a,
                                                 int* __restrict__ adj_b,
                                                 int nE, int nbPer) {
  int blk = blockIdx.x;
  bool first = blk < nbPer;
  const int* ei = first ? ei_a : ei_b;
  const int* offs = first ? offs_a : offs_b;
  int* cur = first ? cur_a : cur_b;
  int* adj = first ? adj_a : adj_b;
  int e = (blk % nbPer) * 256 + threadIdx.x;
  if (e >= nE) return;
  int dst = ei[nE + e];
  int pos = atomicAdd(cur + dst, 1);
  adj[offs[dst] + pos] = ei[e];
}

// ---------------------------------------------------------------------------
// Segment-mean gather, bf16 in/out, fp32 accumulate, 4x edge unroll (R10).
// Adds stay in original sequential order -> bit-identical.
// ---------------------------------------------------------------------------
__device__ __forceinline__ void gather_row(const ushort* __restrict__ x,
                                           const int* __restrict__ offs,
                                           const int* __restrict__ adj,
                                           ushort* __restrict__ m,
                                           int row, int lane) {
  int start = offs[row], end = offs[row + 1];
  float a0 = 0.f, a1 = 0.f, a2 = 0.f, a3 = 0.f;
  int e = start;
  for (; e + 3 < end; e += 4) {
    int s0 = adj[e], s1 = adj[e + 1], s2 = adj[e + 2], s3 = adj[e + 3];
    ushort4 v0 = *(const ushort4*)(x + (size_t)s0 * DIN + lane * 4);
    ushort4 v1 = *(const ushort4*)(x + (size_t)s1 * DIN + lane * 4);
    ushort4 v2 = *(const ushort4*)(x + (size_t)s2 * DIN + lane * 4);
    ushort4 v3 = *(const ushort4*)(x + (size_t)s3 * DIN + lane * 4);
    a0 += b2f(v0.x); a1 += b2f(v0.y); a2 += b2f(v0.z); a3 += b2f(v0.w);
    a0 += b2f(v1.x); a1 += b2f(v1.y); a2 += b2f(v1.z); a3 += b2f(v1.w);
    a0 += b2f(v2.x); a1 += b2f(v2.y); a2 += b2f(v2.z); a3 += b2f(v2.w);
    a0 += b2f(v3.x); a1 += b2f(v3.y); a2 += b2f(v3.z); a3 += b2f(v3.w);
  }
  for (; e < end; ++e) {
    int s = adj[e];
    ushort4 v = *(const ushort4*)(x + (size_t)s * DIN + lane * 4);
    a0 += b2f(v.x); a1 += b2f(v.y); a2 += b2f(v.z); a3 += b2f(v.w);
  }
  float inv = 1.0f / fmaxf((float)(end - start), 1.0f);
  ushort4 o;
  o.x = f2b(a0 * inv); o.y = f2b(a1 * inv); o.z = f2b(a2 * inv); o.w = f2b(a3 * inv);
  *(ushort4*)(m + (size_t)row * DIN + lane * 4) = o;
}

// L0: both relations, no masks (masks moved to prep_kernel)
__global__ __launch_bounds__(256) void gather2_mean_h(
    const ushort* __restrict__ xa, const int* __restrict__ offsa,
    const int* __restrict__ adja, ushort* __restrict__ ma,
    const ushort* __restrict__ xb, const int* __restrict__ offsb,
    const int* __restrict__ adjb, ushort* __restrict__ mb,
    int nRows, int nbPer) {
  int blk = blockIdx.x;
  bool first = blk < nbPer;
  int row = (blk % nbPer) * 4 + (threadIdx.x >> 6);
  if (row >= nRows) return;
  if (first) gather_row(xa, offsa, adja, ma, row, threadIdx.x & 63);
  else       gather_row(xb, offsb, adjb, mb, row, threadIdx.x & 63);
}

// ---------------------------------------------------------------------------
// MFMA dual GEMM body (verified R8-R10): C = dropout(leaky(A1@W1+A2@W2+b)).
// Masks precomputed; async global_load_lds staging; 40KB LDS.
// ---------------------------------------------------------------------------
__device__ __forceinline__ void gemm_body(
    int bid, const ushort* __restrict__ A1, const ushort* __restrict__ A2,
    const ushort* __restrict__ W1t, const ushort* __restrict__ W2t,
    const float* __restrict__ bias, const uint2* __restrict__ mk,
    ushort* __restrict__ C, int M, ushort* sA, ushort* sB) {
  const int tid = threadIdx.x;
  const int wave = tid >> 6, lane = tid & 63;
  const int q = lane >> 4, r = lane & 15;
  const int mbase = bid * GBM;

  const uint2 km = mk[bid * 256 + tid];  // issued early, hidden by K-loop

  f32x4 acc[4][4] = {};

  const int arow = tid >> 2;        // 0..63
  const int akc = (tid & 3) * 8;    // short offset 0,8,16,24
  const int agrow = min(mbase + arow, M - 1);
  const ushort* a1p = A1 + (size_t)agrow * DIN + akc;
  const ushort* a2p = A2 + (size_t)agrow * DIN + akc;
  const ushort* w1b = W1t + (size_t)arow * DIN + akc;
  const ushort* w2b = W2t + (size_t)arow * DIN + akc;
  ushort* ldsA0 = sA + wave * 512;              // sA phase 0
  ushort* ldsA1 = sA + 2048 + wave * 512;       // sA phase 1

#pragma unroll
  for (int t = 0; t < 8; ++t) {
    const int kt = t * 32;
    __syncthreads();  // prior iter's LDS reads done before DMA overwrites
    ld_lds16(a1p + kt, ldsA0);
    ld_lds16(a2p + kt, ldsA1);
#pragma unroll
    for (int c = 0; c < 4; ++c) {
      ld_lds16(w1b + c * (64 * DIN) + kt, sB + c * 2048 + wave * 512);
      ld_lds16(w2b + c * (64 * DIN) + kt, sB + 8192 + c * 2048 + wave * 512);
    }
    __syncthreads();  // drains vmcnt(0): DMA complete
#pragma unroll
    for (int ph = 0; ph < 2; ++ph) {
      bf16x8 af[4], bfr[4];
#pragma unroll
      for (int i = 0; i < 4; ++i)
        af[i] = *(const bf16x8*)&sA[ph * 2048 + (i * 16 + r) * 32 + q * 8];
#pragma unroll
      for (int j = 0; j < 4; ++j)
        bfr[j] = *(const bf16x8*)&sB[ph * 8192 + (wave * 64 + j * 16 + r) * 32 + q * 8];
#pragma unroll
      for (int i = 0; i < 4; ++i)
#pragma unroll
        for (int j = 0; j < 4; ++j)
          acc[i][j] = __builtin_amdgcn_mfma_f32_16x16x32_bf16(af[i], bfr[j],
                                                              acc[i][j], 0, 0, 0);
    }
  }

  // Epilogue: bias + leaky + masked dropout scale + bf16 store
  float bj[4];
#pragma unroll
  for (int j = 0; j < 4; ++j) bj[j] = bias[wave * 64 + j * 16 + r];
#pragma unroll
  for (int i = 0; i < 4; ++i) {
#pragma unroll
    for (int e = 0; e < 4; ++e) {
      int rowg = mbase + i * 16 + q * 4 + e;
      if (rowg >= M) continue;
#pragma unroll
      for (int j = 0; j < 4; ++j) {
        const int s = i * 16 + e * 4 + j;
        int colg = wave * 64 + j * 16 + r;
        float v = acc[i][j][e] + bj[j];
        v = v >= 0.0f ? v : 0.01f * v;
        uint32_t keep = ((s < 32 ? km.x >> s : km.y >> (s - 32)) & 1u);
        v = keep ? v * (1.0f / 0.9f) : 0.0f;
        C[(size_t)rowg * HID + colg] = f2b(v);
      }
    }
  }
}

__global__ __launch_bounds__(256, 4) void gemm_dual_mfma(
    const ushort* __restrict__ A1, const ushort* __restrict__ A2,
    const ushort* __restrict__ W1t, const ushort* __restrict__ W2t,
    const float* __restrict__ bias, const uint2* __restrict__ mk,
    ushort* __restrict__ C, int M) {
  __shared__ ushort sA[2][GBM * 32];
  __shared__ ushort sB[2][HID * 32];
  gemm_body(blockIdx.x, A1, A2, W1t, W2t, bias, mk, C, M, &sA[0][0], &sB[0][0]);
}

// ---------------------------------------------------------------------------
// gemm_gather: L0 new_s gemm (782 blocks) + L1 gather (12500 blocks), one
// swizzled launch. Independent: gemm reads B1h/xs0h writes B0h; gather reads
// B2h writes xt0h (dead after gemm1). Gather latency stalls fill the gemm's
// barrier-drain bubbles. NOTE: gather blocks inherit the 40KB LDS allocation
// (4 blocks/CU cap) — accepted risk, counters arbitrate.
// ---------------------------------------------------------------------------
#define GG_GB 12500                 // gather blocks (NSRC/4)
#define GG_T  (GBLK + GG_GB)        // 13282

__global__ __launch_bounds__(256, 4) void gemm_gather(
    const ushort* __restrict__ A1, const ushort* __restrict__ A2,
    const ushort* __restrict__ W1t, const ushort* __restrict__ W2t,
    const float* __restrict__ bias, const uint2* __restrict__ mk,
    ushort* __restrict__ C, int M,
    const ushort* __restrict__ gx, const int* __restrict__ goffs,
    const int* __restrict__ gadj, ushort* __restrict__ gm, int gRows) {
  __shared__ ushort sA[2][GBM * 32];
  __shared__ ushort sB[2][HID * 32];
  int blk = (int)(((long long)blockIdx.x * 101) % GG_T);  // 101 coprime to 13282
  if (blk < GBLK) {
    gemm_body(blk, A1, A2, W1t, W2t, bias, mk, C, M, &sA[0][0], &sB[0][0]);
  } else {
    int row = (blk - GBLK) * 4 + (threadIdx.x >> 6);
    if (row < gRows) gather_row(gx, goffs, gadj, gm, row, threadIdx.x & 63);
  }
}

// ---------------------------------------------------------------------------
// Final projection: [M,256] bf16 @ [256,16] fp32 + bout -> fp32
// ---------------------------------------------------------------------------
__global__ __launch_bounds__(256) void out_gemm_h(const ushort* __restrict__ X,
                                                  const float* __restrict__ Wout,
                                                  const float* __restrict__ bout,
                                                  float* __restrict__ C, int M) {
  __shared__ float sW[DIN * DOUT];
  int tid = threadIdx.x;
#pragma unroll
  for (int i = 0; i < (DIN * DOUT) / 256; ++i) sW[i * 256 + tid] = Wout[i * 256 + tid];
  __syncthreads();
  int rr = tid >> 4, c = tid & 15;
  int row = blockIdx.x * 16 + rr;
  if (row >= M) return;
  float acc = bout[c];
  const ushort* xp = X + (size_t)row * DIN;
  for (int k = 0; k < DIN; k += 8) {
    uint4 u = *(const uint4*)(xp + k);
    const ushort* us = (const ushort*)&u;
#pragma unroll
    for (int t = 0; t < 8; ++t) acc += b2f(us[t]) * sW[(k + t) * DOUT + c];
  }
  C[(size_t)row * DOUT + c] = acc;
}

// ---------------------------------------------------------------------------
// Workspace (~138 MB < 154 MB proven safe)
// ---------------------------------------------------------------------------
extern "C" void kernel_launch(void* const* d_in, const int* in_sizes, int n_in,
                              void* d_out, int out_size, void* d_ws, size_t ws_size,
                              hipStream_t stream) {
  const float* x_source = (const float*)d_in[0];
  const float* x_target = (const float*)d_in[1];
  const int* ei_st = (const int*)d_in[2];
  const int* ei_ts = (const int*)d_in[3];
  const float* Wl_st = (const float*)d_in[4];
  const float* Wr_st = (const float*)d_in[5];
  const float* b_st  = (const float*)d_in[6];
  const float* Wl_ts = (const float*)d_in[7];
  const float* Wr_ts = (const float*)d_in[8];
  const float* b_ts  = (const float*)d_in[9];
  const float* Wout  = (const float*)d_in[10];
  const float* bout  = (const float*)d_in[11];
  float* out = (float*)d_out;

  const size_t F = (size_t)NSRC * DIN;  // 12.8M elements
  const size_t WM = (size_t)DIN * HID;  // 65536
  const int nbScan = (NSRC + SB - 1) / SB;  // 49 (NSRC==NTGT)
  const size_t intCount = (NTGT + 1) + (NSRC + 1) + 2 * NE + NTGT + NSRC +
                          2 * nbScan + 3 * MASK_DW_PER;
  const size_t need = (5 * F + 6 * WM) * sizeof(ushort) + intCount * sizeof(int);
  if (ws_size < need) return;

  ushort* xs0h = (ushort*)d_ws;
  ushort* xt0h = xs0h + F;
  ushort* B0h  = xt0h + F;
  ushort* B1h  = B0h + F;
  ushort* B2h  = B1h + F;
  ushort* wt0  = B2h + F;       // Wl_st[0]^T
  ushort* wt1  = wt0 + WM;      // Wr_st[0]^T
  ushort* wt2  = wt1 + WM;      // Wl_ts[0]^T
  ushort* wt3  = wt2 + WM;      // Wr_ts[0]^T
  ushort* wt4  = wt3 + WM;      // Wl_ts[1]^T
  ushort* wt5  = wt4 + WM;      // Wr_ts[1]^T
  int* ip      = (int*)(wt5 + WM);
  int* offs_st = ip;
  int* offs_ts = offs_st + NTGT + 1;
  int* adj_st  = offs_ts + NSRC + 1;
  int* adj_ts  = adj_st + NE;
  int* cur_t   = adj_ts + NE;        // [NTGT] + [NSRC] adjacent for one memset
  int* cur_s   = cur_t + NTGT;
  int* bsum    = cur_s + NSRC;       // [2*nbScan]
  uint32_t* masks = (uint32_t*)(bsum + 2 * nbScan);  // [3*MASK_DW_PER]

  const int EB = (NE + 255) / 256;   // 1250
  const int GGB = NTGT / 4;          // 12500

  // ---- Phase 0: zero the histograms, then all independent prep work ----
  hipMemsetAsync(cur_t, 0, (NTGT + NSRC) * sizeof(int), stream);
  PrepArgs pa;
  pa.xs = x_source; pa.xt = x_target; pa.oxs = xs0h; pa.oxt = xt0h;
  pa.wsrc[0] = Wl_st;      pa.wdst[0] = wt0;
  pa.wsrc[1] = Wr_st;      pa.wdst[1] = wt1;
  pa.wsrc[2] = Wl_ts;      pa.wdst[2] = wt2;
  pa.wsrc[3] = Wr_ts;      pa.wdst[3] = wt3;
  pa.wsrc[4] = Wl_ts + WM; pa.wdst[4] = wt4;
  pa.wsrc[5] = Wr_ts + WM; pa.wdst[5] = wt5;
  pa.ei_a = ei_st; pa.ei_b = ei_ts;
  pa.cur_a = cur_t; pa.cur_b = cur_s;
  pa.masks = masks;
  prep_kernel<<<PREP_T, 256, 0, stream>>>(pa);

  // ---- CSR scan + fill ----
  scan_partial<<<2 * nbScan, SB, 0, stream>>>(cur_t, cur_s, bsum, NTGT, nbScan);
  scan_base<<<1, 128, 0, stream>>>(bsum, nbScan);
  scan_final<<<2 * nbScan, SB, 0, stream>>>(cur_t, cur_s, offs_st, offs_ts,
                                            bsum, NTGT, nbScan);
  csr_fill2<<<2 * EB, 256, 0, stream>>>(ei_st, ei_ts, offs_st, offs_ts,
                                        cur_t, cur_s, adj_st, adj_ts, NE, EB);

  // ---- Layer 0 gathers (both relations) ----
  gather2_mean_h<<<2 * GGB, 256, 0, stream>>>(xs0h, offs_st, adj_st, B0h,
                                              xt0h, offs_ts, adj_ts, B1h,
                                              NTGT, GGB);

  // gemm1: new_t -> B2h (mask slice 0 = FOLD[1])
  gemm_dual_mfma<<<GBLK, 256, 0, stream>>>(
      B0h, xt0h, wt0, wt1, b_st, (const uint2*)(masks), B2h, NTGT);

  // gemm2 (new_s -> B0h, slice 1) + L1 gather (B2h -> xt0h) co-scheduled
  gemm_gather<<<GG_T, 256, 0, stream>>>(
      B1h, xs0h, wt2, wt3, b_ts, (const uint2*)(masks + MASK_DW_PER), B0h, NSRC,
      B2h, offs_ts, adj_ts, xt0h, NSRC);

  // gemm3: L1 new_s = (m_s=xt0h, x_s(1)=B0h) -> B2h (slice 2)
  gemm_dual_mfma<<<GBLK, 256, 0, stream>>>(
      xt0h, B0h, wt4, wt5, b_ts + HID, (const uint2*)(masks + 2 * MASK_DW_PER),
      B2h, NSRC);

  out_gemm_h<<<(NSRC + 15) / 16, 256, 0, stream>>>(B2h, Wout, bout, out, NSRC);
}